// Round 3
// baseline (1000.062 us; speedup 1.0000x reference)
//
#include <hip/hip_runtime.h>

#define Bq 8
#define Tq 2048
#define Cq 1024
#define Hq 16
#define Nq 64
#define FFNq 3584
#define EPSq 1e-5f

typedef __bf16 bf8v __attribute__((ext_vector_type(8)));
typedef float f32x4 __attribute__((ext_vector_type(4)));

typedef __attribute__((address_space(1))) const unsigned int GU;
typedef __attribute__((address_space(3))) unsigned int LU;

__device__ __forceinline__ void gload16(const unsigned short* g, unsigned short* l) {
    __builtin_amdgcn_global_load_lds((GU*)g, (LU*)l, 16, 0, 0);
}

__device__ __forceinline__ unsigned short f2bf(float f) {
    unsigned u = __float_as_uint(f);
    u += 0x7fffu + ((u >> 16) & 1u);   // round-to-nearest-even
    return (unsigned short)(u >> 16);
}
__device__ __forceinline__ float bf2f(unsigned short h) {
    return __uint_as_float(((unsigned)h) << 16);
}

// ---------------- diagnostic fill (ws too small) ----------------
__global__ __launch_bounds__(256)
void diag_kernel(float* __restrict__ out, float val) {
    int i = (blockIdx.x * 256 + threadIdx.x) * 4;
    float4 v = make_float4(val, val, val, val);
    *(float4*)(out + i) = v;
}

// ---------------- fp32 -> bf16 conversion, all 8 weights in one launch -------
__global__ __launch_bounds__(256)
void f2bf_all_kernel(const float* __restrict__ s0, const float* __restrict__ s1,
                     const float* __restrict__ s2, const float* __restrict__ s3,
                     const float* __restrict__ s4, const float* __restrict__ s5,
                     const float* __restrict__ s6, const float* __restrict__ s7,
                     unsigned short* __restrict__ d0, unsigned short* __restrict__ d1,
                     unsigned short* __restrict__ d2, unsigned short* __restrict__ d3,
                     unsigned short* __restrict__ d4, unsigned short* __restrict__ d5,
                     unsigned short* __restrict__ d6, unsigned short* __restrict__ d7) {
    int b = blockIdx.x;
    const float* src; unsigned short* dst;
    if      (b < 1024)  { src = s0; dst = d0; }
    else if (b < 2048)  { src = s1; dst = d1; b -= 1024; }
    else if (b < 3072)  { src = s2; dst = d2; b -= 2048; }
    else if (b < 4096)  { src = s3; dst = d3; b -= 3072; }
    else if (b < 5120)  { src = s4; dst = d4; b -= 4096; }
    else if (b < 8704)  { src = s5; dst = d5; b -= 5120; }
    else if (b < 9728)  { src = s6; dst = d6; b -= 8704; }
    else                { src = s7; dst = d7; b -= 9728; }
    int i = (b * 256 + threadIdx.x) * 4;
    float4 v = *(const float4*)(src + i);
    ushort4 o;
    o.x = f2bf(v.x); o.y = f2bf(v.y); o.z = f2bf(v.z); o.w = f2bf(v.w);
    *(ushort4*)(dst + i) = o;
}

// ---------------- block reduction helper (256 threads) ----------------
__device__ __forceinline__ void blockred2(float& a, float& b, float* sm) {
#pragma unroll
    for (int m = 1; m < 64; m <<= 1) { a += __shfl_xor(a, m); b += __shfl_xor(b, m); }
    const int w = threadIdx.x >> 6;
    __syncthreads();
    if ((threadIdx.x & 63) == 0) { sm[w] = a; sm[4 + w] = b; }
    __syncthreads();
    a = sm[0] + sm[1] + sm[2] + sm[3];
    b = sm[4] + sm[5] + sm[6] + sm[7];
}

// ---------------- ln0 + ln1 fused: x -> x0 (fp32), xn (bf16) ----------------
__global__ __launch_bounds__(256)
void ln01_kernel(const float* __restrict__ x,
                 const float* __restrict__ w0, const float* __restrict__ b0,
                 const float* __restrict__ w1, const float* __restrict__ b1,
                 float* __restrict__ x0, unsigned short* __restrict__ xn) {
    __shared__ float sm[8];
    const int tok = blockIdx.x, tid = threadIdx.x, c = tid * 4;
    const size_t base = (size_t)tok * Cq + c;
    float4 v = *(const float4*)(x + base);
    float s = v.x + v.y + v.z + v.w;
    float ss = v.x * v.x + v.y * v.y + v.z * v.z + v.w * v.w;
    blockred2(s, ss, sm);
    float mu = s * (1.f / Cq);
    float rstd = rsqrtf(ss * (1.f / Cq) - mu * mu + EPSq);
    float4 wv = *(const float4*)(w0 + c), bv = *(const float4*)(b0 + c);
    float4 e;
    e.x = (v.x - mu) * rstd * wv.x + bv.x;
    e.y = (v.y - mu) * rstd * wv.y + bv.y;
    e.z = (v.z - mu) * rstd * wv.z + bv.z;
    e.w = (v.w - mu) * rstd * wv.w + bv.w;
    *(float4*)(x0 + base) = e;
    s = e.x + e.y + e.z + e.w;
    ss = e.x * e.x + e.y * e.y + e.z * e.z + e.w * e.w;
    blockred2(s, ss, sm);
    mu = s * (1.f / Cq);
    rstd = rsqrtf(ss * (1.f / Cq) - mu * mu + EPSq);
    wv = *(const float4*)(w1 + c); bv = *(const float4*)(b1 + c);
    ushort4 o;
    o.x = f2bf((e.x - mu) * rstd * wv.x + bv.x);
    o.y = f2bf((e.y - mu) * rstd * wv.y + bv.y);
    o.z = f2bf((e.z - mu) * rstd * wv.z + bv.z);
    o.w = f2bf((e.w - mu) * rstd * wv.w + bv.w);
    *(ushort4*)(xn + base) = o;
}

// ---------------- single layernorm (ln2): fp32 in -> bf16 out ----------------
__global__ __launch_bounds__(256)
void ln_kernel(const float* __restrict__ x, const float* __restrict__ w,
               const float* __restrict__ b, unsigned short* __restrict__ out) {
    __shared__ float sm[8];
    const int tok = blockIdx.x, tid = threadIdx.x, c = tid * 4;
    const size_t base = (size_t)tok * Cq + c;
    float4 v = *(const float4*)(x + base);
    float s = v.x + v.y + v.z + v.w;
    float ss = v.x * v.x + v.y * v.y + v.z * v.z + v.w * v.w;
    blockred2(s, ss, sm);
    float mu = s * (1.f / Cq);
    float rstd = rsqrtf(ss * (1.f / Cq) - mu * mu + EPSq);
    float4 wv = *(const float4*)(w + c), bv = *(const float4*)(b + c);
    ushort4 o;
    o.x = f2bf((v.x - mu) * rstd * wv.x + bv.x);
    o.y = f2bf((v.y - mu) * rstd * wv.y + bv.y);
    o.z = f2bf((v.z - mu) * rstd * wv.z + bv.z);
    o.w = f2bf((v.w - mu) * rstd * wv.w + bv.w);
    *(ushort4*)(out + base) = o;
}

// ---------------- token-shift: 4 mixes in one pass (time-mix) ----------------
__device__ __forceinline__ ushort4 mixpack(float ax, float ay, float az, float aw,
                                           float px, float py, float pz, float pw,
                                           const float4& m) {
    ushort4 o;
    o.x = f2bf(px + m.x * (ax - px));
    o.y = f2bf(py + m.y * (ay - py));
    o.z = f2bf(pz + m.z * (az - pz));
    o.w = f2bf(pw + m.w * (aw - pw));
    return o;
}

__global__ __launch_bounds__(256)
void mix4_kernel(const unsigned short* __restrict__ xn,
                 const float* __restrict__ tmr, const float* __restrict__ tmk,
                 const float* __restrict__ tmv, const float* __restrict__ tmg,
                 ushort4* __restrict__ outR, ushort4* __restrict__ outK,
                 ushort4* __restrict__ outV, ushort4* __restrict__ outG) {
    const int tok = blockIdx.x, tid = threadIdx.x, c = tid * 4;
    const int t = tok & (Tq - 1);
    const size_t base = (size_t)tok * Cq + c;
    ushort4 a = *(const ushort4*)(xn + base);
    ushort4 p = make_ushort4(0, 0, 0, 0);
    if (t) p = *(const ushort4*)(xn + base - Cq);
    float ax = bf2f(a.x), ay = bf2f(a.y), az = bf2f(a.z), aw = bf2f(a.w);
    float px = bf2f(p.x), py = bf2f(p.y), pz = bf2f(p.z), pw = bf2f(p.w);
    const size_t b4 = (size_t)tok * 256 + tid;
    outR[b4] = mixpack(ax, ay, az, aw, px, py, pz, pw, *(const float4*)(tmr + c));
    outK[b4] = mixpack(ax, ay, az, aw, px, py, pz, pw, *(const float4*)(tmk + c));
    outV[b4] = mixpack(ax, ay, az, aw, px, py, pz, pw, *(const float4*)(tmv + c));
    outG[b4] = mixpack(ax, ay, az, aw, px, py, pz, pw, *(const float4*)(tmg + c));
}

// ---------------- token-shift: 2 mixes in one pass (channel-mix) -------------
__global__ __launch_bounds__(256)
void mix2_kernel(const unsigned short* __restrict__ xn,
                 const float* __restrict__ tmk, const float* __restrict__ tmr,
                 ushort4* __restrict__ outK, ushort4* __restrict__ outR) {
    const int tok = blockIdx.x, tid = threadIdx.x, c = tid * 4;
    const int t = tok & (Tq - 1);
    const size_t base = (size_t)tok * Cq + c;
    ushort4 a = *(const ushort4*)(xn + base);
    ushort4 p = make_ushort4(0, 0, 0, 0);
    if (t) p = *(const ushort4*)(xn + base - Cq);
    float ax = bf2f(a.x), ay = bf2f(a.y), az = bf2f(a.z), aw = bf2f(a.w);
    float px = bf2f(p.x), py = bf2f(p.y), pz = bf2f(p.z), pw = bf2f(p.w);
    const size_t b4 = (size_t)tok * 256 + tid;
    outK[b4] = mixpack(ax, ay, az, aw, px, py, pz, pw, *(const float4*)(tmk + c));
    outR[b4] = mixpack(ax, ay, az, aw, px, py, pz, pw, *(const float4*)(tmr + c));
}

// ---------------- 256x256 single-barrier pipelined bf16 MFMA GEMM ------------
// out[m,n] = sum_k A[m,k]*W[n,k].  8 waves (2Mx4N), per-wave 128x64 output.
// BK=32; LDS = 4-slot ring x {A,B} x 16KB = 128 KiB (1 block/CU, 2 waves/SIMD).
// ONE barrier per K-tile (no mid-phase barriers): within tile t all 12 ds_reads
// hit slot t (certified by the PREVIOUS tile-end barrier) and the MFMA cluster
// depends on them only through registers (compiler emits fine-grained lgkmcnt).
// With 2 waves/SIMD un-lockstepped inside the tile, wave B's ds_reads overlap
// wave A's MFMA cluster -> LDS and MFMA pipes run concurrently (m114 mechanism;
// setprio(1) around MFMA arbitrates the role-split, T5 regime).
// Pipeline: stage K-tile t+3 while computing t; counted s_waitcnt vmcnt(8) at
// tile end (2 staged tiles stay in flight across the barrier); tail 8->4->0.
// Certification: at end-of-t, in-flight = S(t+3),S(t+2) = 8 loads -> S(t+1)
// drained -> tile t+1 reads safe.  WAR: S(t+3) writes slot (t-1)&3 whose reads
// completed before the end-of-(t-1) barrier.
// MODE: 1 silu->bf16; 2 res+acc->fp32; 3 relu^2->bf16; 4 sigmoid->bf16;
//       5 res+bf2f(sg)*acc->fp32; 6 plain->bf16.  Requires K%32==0, K>=128,
//       M%256==0, N%256==0, grid%8==0 (all call sites satisfy).
template<int MODE>
__global__ __launch_bounds__(512, 2)
void gemm256(const unsigned short* __restrict__ A, const unsigned short* __restrict__ W,
             int K, int N, float* __restrict__ outF, unsigned short* __restrict__ outB,
             const float* __restrict__ res, const unsigned short* __restrict__ sg) {
    __shared__ unsigned short lds[4][2][8192];   // [slot][A=0/B=1][256*32 elems]
    const int tid = threadIdx.x;
    const int wid = tid >> 6, lane = tid & 63;
    const int wr = wid >> 2, wc = wid & 3;       // wave grid 2 (M) x 4 (N)
    const int l15 = lane & 15, q = lane >> 4;

    // T1: bijective XCD swizzle (grid % 8 == 0), then m-major over nn n-blocks
    const int nn = N >> 8;
    const int q8 = gridDim.x >> 3;
    const int bid = blockIdx.x;
    const int swz = (bid & 7) * q8 + (bid >> 3);
    const int m0 = (swz / nn) * 256;
    const int n0 = (swz % nn) * 256;

    // staging: thread's linear LDS dest d -> pre-swizzled global source.
    // dest byte d: row r=d>>6, chunk k=(d>>4)&3; source chunk = k ^ s(r),
    // s(r) = (r ^ (r>>2)) & 3 = (((d>>6) ^ (d>>8)) & 3).
    const int d0 = tid * 16, d1 = 8192 + tid * 16;           // bytes in 16KB region
    const int p0 = d0 ^ ((((d0 >> 6) ^ (d0 >> 8)) & 3) << 4);
    const int p1 = d1 ^ ((((d1 >> 6) ^ (d1 >> 8)) & 3) << 4);
    const int r0 = p0 >> 6, c0 = (p0 >> 1) & 31;             // rows 0..127
    const int r1 = p1 >> 6, c1 = (p1 >> 1) & 31;             // rows 128..255
    const unsigned short* a0 = A + (size_t)(m0 + r0) * K + c0;
    const unsigned short* a1 = A + (size_t)(m0 + r1) * K + c1;
    const unsigned short* w0 = W + (size_t)(n0 + r0) * K + c0;
    const unsigned short* w1 = W + (size_t)(n0 + r1) * K + c1;

    // fragment read offsets (elems): chunk = q ^ s(row); all fragment row
    // bases are multiples of 16, so s(row) = (l15 ^ (l15>>2)) & 3.
    const int cOff = (q ^ ((l15 ^ (l15 >> 2)) & 3)) * 8;
    const int aBase = (wr * 128 + l15) * 32 + cOff;
    const int bBase = (wc * 64 + l15) * 32 + cOff;

    f32x4 acc[8][4];
#pragma unroll
    for (int mi = 0; mi < 8; ++mi)
#pragma unroll
        for (int ni = 0; ni < 4; ++ni)
            acc[mi][ni] = {0.f, 0.f, 0.f, 0.f};

    const int NT = K >> 5;

    // prologue: stage tiles 0,1,2 (12 loads) -> wait 4 oldest (tile 0) landed
#pragma unroll
    for (int t = 0; t < 3; ++t) {
        unsigned short* La = (unsigned short*)&lds[t][0][wid * 512];
        unsigned short* Lb = (unsigned short*)&lds[t][1][wid * 512];
        gload16(a0, La); gload16(a1, La + 4096);
        gload16(w0, Lb); gload16(w1, Lb + 4096);
        a0 += 32; a1 += 32; w0 += 32; w1 += 32;
    }
    asm volatile("s_waitcnt vmcnt(8)" ::: "memory");
    __builtin_amdgcn_s_barrier();

    for (int t = 0; t < NT; ++t) {
        const int slot = t & 3;
        // stage tile t+3 first (long-latency HBM issue earliest)
        if (t + 3 < NT) {
            const int ps = (t + 3) & 3;
            unsigned short* La = (unsigned short*)&lds[ps][0][wid * 512];
            unsigned short* Lb = (unsigned short*)&lds[ps][1][wid * 512];
            gload16(a0, La); gload16(a1, La + 4096);
            gload16(w0, Lb); gload16(w1, Lb + 4096);
            a0 += 32; a1 += 32; w0 += 32; w1 += 32;
        }
        // all 12 fragment reads for tile t (slot certified by previous barrier)
        bf8v af[8], bb[4];
#pragma unroll
        for (int mi = 0; mi < 8; ++mi)
            af[mi] = *(const bf8v*)&lds[slot][0][aBase + mi * 512];
#pragma unroll
        for (int ni = 0; ni < 4; ++ni)
            bb[ni] = *(const bf8v*)&lds[slot][1][bBase + ni * 512];
        // 32 MFMA; register deps gate on lgkmcnt automatically
        __builtin_amdgcn_s_setprio(1);
#pragma unroll
        for (int mi = 0; mi < 8; ++mi)
#pragma unroll
            for (int ni = 0; ni < 4; ++ni)
                acc[mi][ni] = __builtin_amdgcn_mfma_f32_16x16x32_bf16(af[mi], bb[ni], acc[mi][ni], 0, 0, 0);
        __builtin_amdgcn_s_setprio(0);
        // single tile-end sync: counted vmcnt (never 0 in steady state)
        if (t < NT - 3) {
            asm volatile("s_waitcnt vmcnt(8)" ::: "memory");
            __builtin_amdgcn_s_barrier();
        } else if (t == NT - 3) {
            asm volatile("s_waitcnt vmcnt(4)" ::: "memory");
            __builtin_amdgcn_s_barrier();
        } else if (t == NT - 2) {
            asm volatile("s_waitcnt vmcnt(0)" ::: "memory");
            __builtin_amdgcn_s_barrier();
        }
        // t == NT-1: fall through to epilogue (no LDS use after)
    }

    // ---- epilogue ----
#pragma unroll
    for (int mi = 0; mi < 8; ++mi)
#pragma unroll
        for (int ni = 0; ni < 4; ++ni)
#pragma unroll
            for (int j = 0; j < 4; ++j) {
                const int row = m0 + wr * 128 + mi * 16 + q * 4 + j;
                const int col = n0 + wc * 64 + ni * 16 + l15;
                const size_t idx = (size_t)row * N + col;
                const float a = acc[mi][ni][j];
                if (MODE == 1) {
                    outB[idx] = f2bf(a / (1.f + __expf(-a)));
                } else if (MODE == 2) {
                    outF[idx] = res[idx] + a;
                } else if (MODE == 3) {
                    float tt = fmaxf(a, 0.f);
                    outB[idx] = f2bf(tt * tt);
                } else if (MODE == 4) {
                    outB[idx] = f2bf(1.f / (1.f + __expf(-a)));
                } else if (MODE == 5) {
                    outF[idx] = res[idx] + bf2f(sg[idx]) * a;
                } else {
                    outB[idx] = f2bf(a);
                }
            }
}

// ---------------- WKV5: chunked linear attention + fused GroupNorm*gate ------
__global__ __launch_bounds__(256)
void wkv_kernel(const unsigned short* __restrict__ r, const unsigned short* __restrict__ k,
                const unsigned short* __restrict__ v, const unsigned short* __restrict__ g,
                const float* __restrict__ decay, const float* __restrict__ faaaa,
                const float* __restrict__ lnxw, const float* __restrict__ lnxb,
                unsigned short* __restrict__ ao) {
    __shared__ unsigned short rp[64 * 72], km[64 * 72], kdT[64 * 72];
    __shared__ unsigned short VT[64 * 72], Abf[64 * 72], ScT[64 * 72], Gsh[64 * 72];
    __shared__ float Dt[64];
    const int tid = threadIdx.x;
    const int bh = blockIdx.x, b = bh >> 4, h = bh & 15;
    const int tr = tid >> 2, g4 = tid & 3, i0 = g4 * 16;
    const int wv = tid >> 6, lane = tid & 63, l15 = lane & 15, q = lane >> 4;
    const float LOG2E = 1.44269504088896340736f;

    float l2w[16], uu[16];
#pragma unroll
    for (int ii = 0; ii < 16; ++ii) {
        l2w[ii] = -__expf(decay[h * Nq + i0 + ii]) * LOG2E;
        uu[ii] = faaaa[h * Nq + i0 + ii];
    }
    float ewL[4];
#pragma unroll
    for (int jr = 0; jr < 4; ++jr) {
        float lw = -__expf(decay[h * Nq + 16 * wv + q * 4 + jr]) * LOG2E;
        ewL[jr] = exp2f(64.f * lw);
    }
    const int colbase = h * Nq;
    float lwj[4], lbj[4];
#pragma unroll
    for (int nt = 0; nt < 4; ++nt) {
        lwj[nt] = lnxw[colbase + 16 * nt + l15];
        lbj[nt] = lnxb[colbase + 16 * nt + l15];
    }
    f32x4 S[4];
#pragma unroll
    for (int nt = 0; nt < 4; ++nt) S[nt] = {0.f, 0.f, 0.f, 0.f};
    for (int idx = tid; idx < 64 * 72; idx += 256) ScT[idx] = 0;
    __syncthreads();

    const size_t rowbase = (size_t)b * Tq;

    for (int c = 0; c < 32; ++c) {
        const size_t grow = (rowbase + c * 64 + tr) * Cq + colbase + i0;
        unsigned short rs_[16], ks_[16], vs_[16];
        *(uint4*)&rs_[0] = *(const uint4*)(r + grow);
        *(uint4*)&rs_[8] = *(const uint4*)(r + grow + 8);
        *(uint4*)&ks_[0] = *(const uint4*)(k + grow);
        *(uint4*)&ks_[8] = *(const uint4*)(k + grow + 8);
        *(uint4*)&vs_[0] = *(const uint4*)(v + grow);
        *(uint4*)&vs_[8] = *(const uint4*)(v + grow + 8);
        *(uint4*)&Gsh[tr * 72 + i0] = *(const uint4*)(g + grow);
        *(uint4*)&Gsh[tr * 72 + i0 + 8] = *(const uint4*)(g + grow + 8);
        float pd = 0.f;
        const float ftr = (float)tr;
#pragma unroll
        for (int ii = 0; ii < 16; ++ii) {
            float rf = bf2f(rs_[ii]), kf = bf2f(ks_[ii]);
            rp[tr * 72 + i0 + ii] = f2bf(rf * exp2f(ftr * l2w[ii]));
            km[tr * 72 + i0 + ii] = f2bf(kf * exp2f(-(ftr + 1.f) * l2w[ii]));
            kdT[(i0 + ii) * 72 + tr] = f2bf(kf * exp2f((63.f - ftr) * l2w[ii]));
            VT[(i0 + ii) * 72 + tr] = vs_[ii];
            pd += rf * uu[ii] * kf;
        }
        pd += __shfl_xor(pd, 1);
        pd += __shfl_xor(pd, 2);
        if (g4 == 0) Dt[tr] = pd;
        __syncthreads();

        f32x4 accA[4];
#pragma unroll
        for (int nt = 0; nt < 4; ++nt) accA[nt] = {0.f, 0.f, 0.f, 0.f};
#pragma unroll
        for (int ks = 0; ks < 2; ++ks) {
            bf8v a = *(const bf8v*)&rp[(16 * wv + l15) * 72 + ks * 32 + q * 8];
#pragma unroll
            for (int nt = 0; nt < 4; ++nt) {
                bf8v bbv = *(const bf8v*)&km[(16 * nt + l15) * 72 + ks * 32 + q * 8];
                accA[nt] = __builtin_amdgcn_mfma_f32_16x16x32_bf16(a, bbv, accA[nt], 0, 0, 0);
            }
        }
#pragma unroll
        for (int nt = 0; nt < 4; ++nt)
#pragma unroll
            for (int jr = 0; jr < 4; ++jr) {
                const int t = 16 * wv + q * 4 + jr, s = 16 * nt + l15;
                const float a = accA[nt][jr];
                const float val = (s < t) ? a : ((s == t) ? Dt[t] : 0.f);
                Abf[t * 72 + s] = f2bf(val);
            }

        f32x4 accY[4];
#pragma unroll
        for (int nt = 0; nt < 4; ++nt) accY[nt] = {0.f, 0.f, 0.f, 0.f};
#pragma unroll
        for (int ks = 0; ks < 2; ++ks) {
            bf8v a = *(const bf8v*)&Abf[(16 * wv + l15) * 72 + ks * 32 + q * 8];
#pragma unroll
            for (int nt = 0; nt < 4; ++nt) {
                bf8v bbv = *(const bf8v*)&VT[(16 * nt + l15) * 72 + ks * 32 + q * 8];
                accY[nt] = __builtin_amdgcn_mfma_f32_16x16x32_bf16(a, bbv, accY[nt], 0, 0, 0);
            }
        }
#pragma unroll
        for (int ks = 0; ks < 2; ++ks) {
            bf8v a = *(const bf8v*)&rp[(16 * wv + l15) * 72 + ks * 32 + q * 8];
#pragma unroll
            for (int nt = 0; nt < 4; ++nt) {
                bf8v bbv = *(const bf8v*)&ScT[(16 * nt + l15) * 72 + ks * 32 + q * 8];
                accY[nt] = __builtin_amdgcn_mfma_f32_16x16x32_bf16(a, bbv, accY[nt], 0, 0, 0);
            }
        }

        float sum_[4] = {0.f, 0.f, 0.f, 0.f}, sq_[4] = {0.f, 0.f, 0.f, 0.f};
#pragma unroll
        for (int nt = 0; nt < 4; ++nt)
#pragma unroll
            for (int jr = 0; jr < 4; ++jr) {
                float yv = accY[nt][jr] * 0.125f;
                accY[nt][jr] = yv;
                sum_[jr] += yv;
                sq_[jr] += yv * yv;
            }
#pragma unroll
        for (int m = 1; m < 16; m <<= 1)
#pragma unroll
            for (int jr = 0; jr < 4; ++jr) {
                sum_[jr] += __shfl_xor(sum_[jr], m);
                sq_[jr] += __shfl_xor(sq_[jr], m);
            }
        float mu_[4], rstd_[4];
#pragma unroll
        for (int jr = 0; jr < 4; ++jr) {
            mu_[jr] = sum_[jr] * (1.f / Nq);
            rstd_[jr] = rsqrtf(sq_[jr] * (1.f / Nq) - mu_[jr] * mu_[jr] + EPSq);
        }
#pragma unroll
        for (int nt = 0; nt < 4; ++nt)
#pragma unroll
            for (int jr = 0; jr < 4; ++jr) {
                const int t = 16 * wv + q * 4 + jr;
                const float gate = bf2f(Gsh[t * 72 + 16 * nt + l15]);
                const float val = (accY[nt][jr] - mu_[jr]) * rstd_[jr] * lwj[nt] + lbj[nt];
                ao[(rowbase + c * 64 + t) * Cq + colbase + 16 * nt + l15] = f2bf(val * gate);
            }

        f32x4 accU[4];
#pragma unroll
        for (int nt = 0; nt < 4; ++nt) accU[nt] = {0.f, 0.f, 0.f, 0.f};
#pragma unroll
        for (int ks = 0; ks < 2; ++ks) {
            bf8v a = *(const bf8v*)&kdT[(16 * wv + l15) * 72 + ks * 32 + q * 8];
#pragma unroll
            for (int nt = 0; nt < 4; ++nt) {
                bf8v bbv = *(const bf8v*)&VT[(16 * nt + l15) * 72 + ks * 32 + q * 8];
                accU[nt] = __builtin_amdgcn_mfma_f32_16x16x32_bf16(a, bbv, accU[nt], 0, 0, 0);
            }
        }
        __syncthreads();
#pragma unroll
        for (int nt = 0; nt < 4; ++nt) {
#pragma unroll
            for (int jr = 0; jr < 4; ++jr)
                S[nt][jr] = ewL[jr] * S[nt][jr] + accU[nt][jr];
            ushort4 sc;
            sc.x = f2bf(S[nt][0]); sc.y = f2bf(S[nt][1]);
            sc.z = f2bf(S[nt][2]); sc.w = f2bf(S[nt][3]);
            *(ushort4*)&ScT[(16 * nt + l15) * 72 + 16 * wv + q * 4] = sc;
        }
        __syncthreads();
    }
}

// ---------------- launcher ----------------
extern "C" void kernel_launch(void* const* d_in, const int* in_sizes, int n_in,
                              void* d_out, int out_size, void* d_ws, size_t ws_size,
                              hipStream_t stream) {
    const float* x     = (const float*)d_in[0];
    const float* ln0w  = (const float*)d_in[1];
    const float* ln0b  = (const float*)d_in[2];
    const float* ln1w  = (const float*)d_in[3];
    const float* ln1b  = (const float*)d_in[4];
    const float* ln2w  = (const float*)d_in[5];
    const float* ln2b  = (const float*)d_in[6];
    const float* atmk  = (const float*)d_in[7];
    const float* atmv  = (const float*)d_in[8];
    const float* atmr  = (const float*)d_in[9];
    const float* atmg  = (const float*)d_in[10];
    const float* decay = (const float*)d_in[11];
    const float* faaaa = (const float*)d_in[12];
    const float* aWr   = (const float*)d_in[13];
    const float* aWk   = (const float*)d_in[14];
    const float* aWv   = (const float*)d_in[15];
    const float* aWg   = (const float*)d_in[16];
    const float* aWo   = (const float*)d_in[17];
    const float* lnxw  = (const float*)d_in[18];
    const float* lnxb  = (const float*)d_in[19];
    const float* ftmk  = (const float*)d_in[20];
    const float* ftmr  = (const float*)d_in[21];
    const float* fWk   = (const float*)d_in[22];
    const float* fWr   = (const float*)d_in[23];
    const float* fWv   = (const float*)d_in[24];

    const size_t MB = 1024ull * 1024ull;
    const size_t WS_NEEDED = 250 * MB;
    dim3 blk(256);

    if (ws_size < WS_NEEDED) {
        diag_kernel<<<out_size / 1024, blk, 0, stream>>>((float*)d_out,
            1000.f + (float)((double)ws_size / (double)MB));
        return;
    }

    char* ws = (char*)d_ws;
    unsigned short* WR  = (unsigned short*)(ws + 0 * MB);
    unsigned short* WK  = (unsigned short*)(ws + 2 * MB);
    unsigned short* WV  = (unsigned short*)(ws + 4 * MB);
    unsigned short* WG  = (unsigned short*)(ws + 6 * MB);
    unsigned short* WO  = (unsigned short*)(ws + 8 * MB);
    unsigned short* FWK = (unsigned short*)(ws + 10 * MB);
    unsigned short* FWR = (unsigned short*)(ws + 17 * MB);
    unsigned short* FWV = (unsigned short*)(ws + 19 * MB);
    unsigned short* XN  = (unsigned short*)(ws + 26 * MB);
    unsigned short* MXR = (unsigned short*)(ws + 58 * MB);
    unsigned short* MXK = (unsigned short*)(ws + 90 * MB);
    unsigned short* MXV = (unsigned short*)(ws + 122 * MB);
    unsigned short* MXG = (unsigned short*)(ws + 154 * MB);
    unsigned short* Rb  = (unsigned short*)(ws + 186 * MB);
    unsigned short* Kb  = (unsigned short*)(ws + 58 * MB);
    unsigned short* Vb  = (unsigned short*)(ws + 90 * MB);
    unsigned short* Gb  = (unsigned short*)(ws + 122 * MB);
    unsigned short* AO  = (unsigned short*)(ws + 154 * MB);
    unsigned short* XK2 = (unsigned short*)(ws + 58 * MB);
    unsigned short* XR2 = (unsigned short*)(ws + 90 * MB);
    unsigned short* KF  = (unsigned short*)(ws + 122 * MB);
    unsigned short* SRb = (unsigned short*)(ws + 26 * MB);
    float*          X0  = (float*)d_out;

    const int NTOK = Bq * Tq;  // 16384
    dim3 blk512(512);
    const int gsq = (NTOK / 256) * (Cq / 256);    // 64*4  = 256 blocks
    const int gup = (NTOK / 256) * (FFNq / 256);  // 64*14 = 896 blocks

    f2bf_all_kernel<<<13312, blk, 0, stream>>>(aWr, aWk, aWv, aWg, aWo, fWk, fWr, fWv,
                                               WR, WK, WV, WG, WO, FWK, FWR, FWV);

    ln01_kernel<<<NTOK, blk, 0, stream>>>(x, ln0w, ln0b, ln1w, ln1b, X0, XN);

    mix4_kernel<<<NTOK, blk, 0, stream>>>(XN, atmr, atmk, atmv, atmg,
                                          (ushort4*)MXR, (ushort4*)MXK,
                                          (ushort4*)MXV, (ushort4*)MXG);

    gemm256<6><<<gsq, blk512, 0, stream>>>(MXR, WR, Cq, Cq, nullptr, Rb, nullptr, nullptr);
    gemm256<6><<<gsq, blk512, 0, stream>>>(MXK, WK, Cq, Cq, nullptr, Kb, nullptr, nullptr);
    gemm256<6><<<gsq, blk512, 0, stream>>>(MXV, WV, Cq, Cq, nullptr, Vb, nullptr, nullptr);
    gemm256<1><<<gsq, blk512, 0, stream>>>(MXG, WG, Cq, Cq, nullptr, Gb, nullptr, nullptr);

    wkv_kernel<<<Bq * Hq, blk, 0, stream>>>(Rb, Kb, Vb, Gb, decay, faaaa, lnxw, lnxb, AO);
    gemm256<2><<<gsq, blk512, 0, stream>>>(AO, WO, Cq, Cq, X0, nullptr, X0, nullptr);

    ln_kernel<<<NTOK, blk, 0, stream>>>(X0, ln2w, ln2b, XN);
    mix2_kernel<<<NTOK, blk, 0, stream>>>(XN, ftmk, ftmr, (ushort4*)XK2, (ushort4*)XR2);
    gemm256<3><<<gup, blk512, 0, stream>>>(XK2, FWK, Cq, FFNq, nullptr, KF, nullptr, nullptr);
    gemm256<4><<<gsq, blk512, 0, stream>>>(XR2, FWR, Cq, Cq, nullptr, SRb, nullptr, nullptr);
    gemm256<5><<<gsq, blk512, 0, stream>>>(KF, FWV, FFNq, Cq, X0, nullptr, X0, SRb);
}

// Round 4
// 963.435 us; speedup vs baseline: 1.0380x; 1.0380x over previous
//
#include <hip/hip_runtime.h>

#define Bq 8
#define Tq 2048
#define Cq 1024
#define Hq 16
#define Nq 64
#define FFNq 3584
#define EPSq 1e-5f

typedef __bf16 bf8v __attribute__((ext_vector_type(8)));
typedef float f32x4 __attribute__((ext_vector_type(4)));

typedef __attribute__((address_space(1))) const unsigned int GU;
typedef __attribute__((address_space(3))) unsigned int LU;

__device__ __forceinline__ void gload16(const unsigned short* g, unsigned short* l) {
    __builtin_amdgcn_global_load_lds((GU*)g, (LU*)l, 16, 0, 0);
}

__device__ __forceinline__ unsigned short f2bf(float f) {
    unsigned u = __float_as_uint(f);
    u += 0x7fffu + ((u >> 16) & 1u);   // round-to-nearest-even
    return (unsigned short)(u >> 16);
}
__device__ __forceinline__ float bf2f(unsigned short h) {
    return __uint_as_float(((unsigned)h) << 16);
}

// ---------------- diagnostic fill (ws too small) ----------------
__global__ __launch_bounds__(256)
void diag_kernel(float* __restrict__ out, float val) {
    int i = (blockIdx.x * 256 + threadIdx.x) * 4;
    float4 v = make_float4(val, val, val, val);
    *(float4*)(out + i) = v;
}

// ---------------- fp32 -> bf16 conversion, all 8 weights in one launch -------
__global__ __launch_bounds__(256)
void f2bf_all_kernel(const float* __restrict__ s0, const float* __restrict__ s1,
                     const float* __restrict__ s2, const float* __restrict__ s3,
                     const float* __restrict__ s4, const float* __restrict__ s5,
                     const float* __restrict__ s6, const float* __restrict__ s7,
                     unsigned short* __restrict__ d0, unsigned short* __restrict__ d1,
                     unsigned short* __restrict__ d2, unsigned short* __restrict__ d3,
                     unsigned short* __restrict__ d4, unsigned short* __restrict__ d5,
                     unsigned short* __restrict__ d6, unsigned short* __restrict__ d7) {
    int b = blockIdx.x;
    const float* src; unsigned short* dst;
    if      (b < 1024)  { src = s0; dst = d0; }
    else if (b < 2048)  { src = s1; dst = d1; b -= 1024; }
    else if (b < 3072)  { src = s2; dst = d2; b -= 2048; }
    else if (b < 4096)  { src = s3; dst = d3; b -= 3072; }
    else if (b < 5120)  { src = s4; dst = d4; b -= 4096; }
    else if (b < 8704)  { src = s5; dst = d5; b -= 5120; }
    else if (b < 9728)  { src = s6; dst = d6; b -= 8704; }
    else                { src = s7; dst = d7; b -= 9728; }
    int i = (b * 256 + threadIdx.x) * 4;
    float4 v = *(const float4*)(src + i);
    ushort4 o;
    o.x = f2bf(v.x); o.y = f2bf(v.y); o.z = f2bf(v.z); o.w = f2bf(v.w);
    *(ushort4*)(dst + i) = o;
}

// ---------------- block reduction helper (256 threads) ----------------
__device__ __forceinline__ void blockred2(float& a, float& b, float* sm) {
#pragma unroll
    for (int m = 1; m < 64; m <<= 1) { a += __shfl_xor(a, m); b += __shfl_xor(b, m); }
    const int w = threadIdx.x >> 6;
    __syncthreads();
    if ((threadIdx.x & 63) == 0) { sm[w] = a; sm[4 + w] = b; }
    __syncthreads();
    a = sm[0] + sm[1] + sm[2] + sm[3];
    b = sm[4] + sm[5] + sm[6] + sm[7];
}

// ---------------- ln0 + ln1 fused: x -> x0 (fp32), xn (bf16) ----------------
__global__ __launch_bounds__(256)
void ln01_kernel(const float* __restrict__ x,
                 const float* __restrict__ w0, const float* __restrict__ b0,
                 const float* __restrict__ w1, const float* __restrict__ b1,
                 float* __restrict__ x0, unsigned short* __restrict__ xn) {
    __shared__ float sm[8];
    const int tok = blockIdx.x, tid = threadIdx.x, c = tid * 4;
    const size_t base = (size_t)tok * Cq + c;
    float4 v = *(const float4*)(x + base);
    float s = v.x + v.y + v.z + v.w;
    float ss = v.x * v.x + v.y * v.y + v.z * v.z + v.w * v.w;
    blockred2(s, ss, sm);
    float mu = s * (1.f / Cq);
    float rstd = rsqrtf(ss * (1.f / Cq) - mu * mu + EPSq);
    float4 wv = *(const float4*)(w0 + c), bv = *(const float4*)(b0 + c);
    float4 e;
    e.x = (v.x - mu) * rstd * wv.x + bv.x;
    e.y = (v.y - mu) * rstd * wv.y + bv.y;
    e.z = (v.z - mu) * rstd * wv.z + bv.z;
    e.w = (v.w - mu) * rstd * wv.w + bv.w;
    *(float4*)(x0 + base) = e;
    s = e.x + e.y + e.z + e.w;
    ss = e.x * e.x + e.y * e.y + e.z * e.z + e.w * e.w;
    blockred2(s, ss, sm);
    mu = s * (1.f / Cq);
    rstd = rsqrtf(ss * (1.f / Cq) - mu * mu + EPSq);
    wv = *(const float4*)(w1 + c); bv = *(const float4*)(b1 + c);
    ushort4 o;
    o.x = f2bf((e.x - mu) * rstd * wv.x + bv.x);
    o.y = f2bf((e.y - mu) * rstd * wv.y + bv.y);
    o.z = f2bf((e.z - mu) * rstd * wv.z + bv.z);
    o.w = f2bf((e.w - mu) * rstd * wv.w + bv.w);
    *(ushort4*)(xn + base) = o;
}

// ---------------- single layernorm (ln2): fp32 in -> bf16 out ----------------
__global__ __launch_bounds__(256)
void ln_kernel(const float* __restrict__ x, const float* __restrict__ w,
               const float* __restrict__ b, unsigned short* __restrict__ out) {
    __shared__ float sm[8];
    const int tok = blockIdx.x, tid = threadIdx.x, c = tid * 4;
    const size_t base = (size_t)tok * Cq + c;
    float4 v = *(const float4*)(x + base);
    float s = v.x + v.y + v.z + v.w;
    float ss = v.x * v.x + v.y * v.y + v.z * v.z + v.w * v.w;
    blockred2(s, ss, sm);
    float mu = s * (1.f / Cq);
    float rstd = rsqrtf(ss * (1.f / Cq) - mu * mu + EPSq);
    float4 wv = *(const float4*)(w + c), bv = *(const float4*)(b + c);
    ushort4 o;
    o.x = f2bf((v.x - mu) * rstd * wv.x + bv.x);
    o.y = f2bf((v.y - mu) * rstd * wv.y + bv.y);
    o.z = f2bf((v.z - mu) * rstd * wv.z + bv.z);
    o.w = f2bf((v.w - mu) * rstd * wv.w + bv.w);
    *(ushort4*)(out + base) = o;
}

// ---------------- token-shift: 4 mixes in one pass (time-mix) ----------------
__device__ __forceinline__ ushort4 mixpack(float ax, float ay, float az, float aw,
                                           float px, float py, float pz, float pw,
                                           const float4& m) {
    ushort4 o;
    o.x = f2bf(px + m.x * (ax - px));
    o.y = f2bf(py + m.y * (ay - py));
    o.z = f2bf(pz + m.z * (az - pz));
    o.w = f2bf(pw + m.w * (aw - pw));
    return o;
}

__global__ __launch_bounds__(256)
void mix4_kernel(const unsigned short* __restrict__ xn,
                 const float* __restrict__ tmr, const float* __restrict__ tmk,
                 const float* __restrict__ tmv, const float* __restrict__ tmg,
                 ushort4* __restrict__ outR, ushort4* __restrict__ outK,
                 ushort4* __restrict__ outV, ushort4* __restrict__ outG) {
    const int tok = blockIdx.x, tid = threadIdx.x, c = tid * 4;
    const int t = tok & (Tq - 1);
    const size_t base = (size_t)tok * Cq + c;
    ushort4 a = *(const ushort4*)(xn + base);
    ushort4 p = make_ushort4(0, 0, 0, 0);
    if (t) p = *(const ushort4*)(xn + base - Cq);
    float ax = bf2f(a.x), ay = bf2f(a.y), az = bf2f(a.z), aw = bf2f(a.w);
    float px = bf2f(p.x), py = bf2f(p.y), pz = bf2f(p.z), pw = bf2f(p.w);
    const size_t b4 = (size_t)tok * 256 + tid;
    outR[b4] = mixpack(ax, ay, az, aw, px, py, pz, pw, *(const float4*)(tmr + c));
    outK[b4] = mixpack(ax, ay, az, aw, px, py, pz, pw, *(const float4*)(tmk + c));
    outV[b4] = mixpack(ax, ay, az, aw, px, py, pz, pw, *(const float4*)(tmv + c));
    outG[b4] = mixpack(ax, ay, az, aw, px, py, pz, pw, *(const float4*)(tmg + c));
}

// ---------------- token-shift: 2 mixes in one pass (channel-mix) -------------
__global__ __launch_bounds__(256)
void mix2_kernel(const unsigned short* __restrict__ xn,
                 const float* __restrict__ tmk, const float* __restrict__ tmr,
                 ushort4* __restrict__ outK, ushort4* __restrict__ outR) {
    const int tok = blockIdx.x, tid = threadIdx.x, c = tid * 4;
    const int t = tok & (Tq - 1);
    const size_t base = (size_t)tok * Cq + c;
    ushort4 a = *(const ushort4*)(xn + base);
    ushort4 p = make_ushort4(0, 0, 0, 0);
    if (t) p = *(const ushort4*)(xn + base - Cq);
    float ax = bf2f(a.x), ay = bf2f(a.y), az = bf2f(a.z), aw = bf2f(a.w);
    float px = bf2f(p.x), py = bf2f(p.y), pz = bf2f(p.z), pw = bf2f(p.w);
    const size_t b4 = (size_t)tok * 256 + tid;
    outK[b4] = mixpack(ax, ay, az, aw, px, py, pz, pw, *(const float4*)(tmk + c));
    outR[b4] = mixpack(ax, ay, az, aw, px, py, pz, pw, *(const float4*)(tmr + c));
}

// ---------------- 256x256 m201-style 2-phase/K-step bf16 MFMA GEMM -----------
// out[m,n] = sum_k A[m,k]*W[n,k].  8 waves (2Mx4N), per-wave 128x64 output.
// K-step = 32.  LDS = 8 regions x 16KB = 128 KiB: A(j) -> region [j&3],
// B(j) -> region [4+(j&3)]; region layout [256 rows][32 cols] bf16 (64B rows).
// Per K-step k, TWO phases (m201 template shape):
//   odd : stage A(k+3) (2 gload) ; ds_read a[0:4],b[0:4] (8 x b128) ;
//         barrier ; lgkmcnt(0)+sched_barrier ; setprio1 ; 16 MFMA (mi0-3) ;
//         setprio0 ; barrier
//   even: stage B(k+3) ; ds_read a[4:8] (4) ; barrier ; lgkmcnt(0)+SB ;
//         16 MFMA (mi4-7) ; vmcnt(8) ; barrier
// Certification (per-wave FIFO, 2 loads/stage): vmcnt(8) at even-phase end
// leaves only the last 4 stages uncertified = {A,B}(k+2),{A,B}(k+3) ->
// {A,B}(k+1) provably resident for the next K-step's reads (lag 5-7 phases).
// Tail: vmcnt 8 -> 4 -> 0.  WAR: region j&3 re-staged at k=j-3, >=1 phase
// after the last certified read of (j-4) -- safe by the phase barriers.
// Swizzle: LDS(row,u) holds global chunk u^(row&3); frag read chunk
// q^(l15&3) -> 2 lanes/bank (free); staging source pre-swizzled, dest linear.
// MODE: 1 silu->bf16; 2 res+acc->fp32; 3 relu^2->bf16; 4 sigmoid->bf16;
//       5 res+bf2f(sg)*acc->fp32; 6 plain->bf16.  Requires K%32==0, K>=192,
//       M%256==0, N%256==0, grid%8==0 (all call sites satisfy).
template<int MODE>
__global__ __launch_bounds__(512, 2)
void gemm256(const unsigned short* __restrict__ A, const unsigned short* __restrict__ W,
             int K, int N, float* __restrict__ outF, unsigned short* __restrict__ outB,
             const float* __restrict__ res, const unsigned short* __restrict__ sg) {
    __shared__ unsigned short lds[8][8192];
    const int tid = threadIdx.x;
    const int wid = tid >> 6, lane = tid & 63;
    const int wr = wid >> 2, wc = wid & 3;       // wave grid 2 (M) x 4 (N)
    const int l15 = lane & 15, q = lane >> 4;

    // T1: bijective XCD swizzle (grid % 8 == 0), m-major over nn n-blocks
    const int nn = N >> 8;
    const int q8 = gridDim.x >> 3;
    const int bid = blockIdx.x;
    const int swz = (bid & 7) * q8 + (bid >> 3);
    const int m0 = (swz / nn) * 256;
    const int n0 = (swz % nn) * 256;

    // staging: thread covers rows (tid>>2) and 128+(tid>>2) of the 256-row
    // region; source chunk pre-swizzled: (tid&3) ^ ((tid>>2)&3).
    const int srow = tid >> 2;
    const int scol = ((tid & 3) ^ ((tid >> 2) & 3)) * 8;
    const unsigned short* aS0 = A + (size_t)(m0 + srow) * K + scol;
    const unsigned short* aS1 = A + (size_t)(m0 + 128 + srow) * K + scol;
    const unsigned short* wS0 = W + (size_t)(n0 + srow) * K + scol;
    const unsigned short* wS1 = W + (size_t)(n0 + 128 + srow) * K + scol;

    // fragment read offsets (elems): chunk = q ^ (row&3), row&3 == l15&3
    const int fco = (q ^ (l15 & 3)) * 8;
    const int aOff = (wr * 128 + l15) * 32 + fco;   // + mi*512
    const int bOff = (wc * 64 + l15) * 32 + fco;    // + ni*512

    f32x4 acc[8][4];
#pragma unroll
    for (int mi = 0; mi < 8; ++mi)
#pragma unroll
        for (int ni = 0; ni < 4; ++ni)
            acc[mi][ni] = {0.f, 0.f, 0.f, 0.f};

    const int NJ = K >> 5;

    // prologue: stage {A,B}(0),(1),(2) = 12 loads; vmcnt(8) certifies A0,B0
#pragma unroll
    for (int j = 0; j < 3; ++j) {
        unsigned short* La = &lds[j][tid * 8];
        unsigned short* Lb = &lds[4 + j][tid * 8];
        gload16(aS0 + j * 32, La); gload16(aS1 + j * 32, La + 4096);
        gload16(wS0 + j * 32, Lb); gload16(wS1 + j * 32, Lb + 4096);
    }
    asm volatile("s_waitcnt vmcnt(8)" ::: "memory");
    __builtin_amdgcn_s_barrier();

    bf8v a[4], b[4];
    for (int k = 0; k < NJ; ++k) {
        const int rg = k & 3;
        const unsigned short* LA = &lds[rg][0];
        const unsigned short* LB = &lds[4 + rg][0];
        const bool st = (k + 3) < NJ;
        const int sj = (k + 3) & 3;

        // ---- odd phase: stage A(k+3); read a[0:4] + b[0:4]; MFMA mi0-3 ----
        if (st) {
            unsigned short* La = &lds[sj][tid * 8];
            gload16(aS0 + (k + 3) * 32, La);
            gload16(aS1 + (k + 3) * 32, La + 4096);
        }
#pragma unroll
        for (int i = 0; i < 4; ++i) a[i] = *(const bf8v*)&LA[aOff + i * 512];
#pragma unroll
        for (int i = 0; i < 4; ++i) b[i] = *(const bf8v*)&LB[bOff + i * 512];
        __builtin_amdgcn_s_barrier();
        asm volatile("s_waitcnt lgkmcnt(0)" ::: "memory");
        __builtin_amdgcn_sched_barrier(0);
        __builtin_amdgcn_s_setprio(1);
#pragma unroll
        for (int mi = 0; mi < 4; ++mi)
#pragma unroll
            for (int ni = 0; ni < 4; ++ni)
                acc[mi][ni] = __builtin_amdgcn_mfma_f32_16x16x32_bf16(a[mi], b[ni], acc[mi][ni], 0, 0, 0);
        __builtin_amdgcn_s_setprio(0);
        __builtin_amdgcn_s_barrier();

        // ---- even phase: stage B(k+3); read a[4:8]; MFMA mi4-7; vmcnt ----
        if (st) {
            unsigned short* Lb = &lds[4 + sj][tid * 8];
            gload16(wS0 + (k + 3) * 32, Lb);
            gload16(wS1 + (k + 3) * 32, Lb + 4096);
        }
#pragma unroll
        for (int i = 0; i < 4; ++i) a[i] = *(const bf8v*)&LA[aOff + (4 + i) * 512];
        __builtin_amdgcn_s_barrier();
        asm volatile("s_waitcnt lgkmcnt(0)" ::: "memory");
        __builtin_amdgcn_sched_barrier(0);
        __builtin_amdgcn_s_setprio(1);
#pragma unroll
        for (int mi = 0; mi < 4; ++mi)
#pragma unroll
            for (int ni = 0; ni < 4; ++ni)
                acc[4 + mi][ni] = __builtin_amdgcn_mfma_f32_16x16x32_bf16(a[mi], b[ni], acc[4 + mi][ni], 0, 0, 0);
        __builtin_amdgcn_s_setprio(0);
        if (k <= NJ - 4)      { asm volatile("s_waitcnt vmcnt(8)" ::: "memory"); }
        else if (k == NJ - 3) { asm volatile("s_waitcnt vmcnt(4)" ::: "memory"); }
        else if (k == NJ - 2) { asm volatile("s_waitcnt vmcnt(0)" ::: "memory"); }
        __builtin_amdgcn_s_barrier();
    }

    // ---- epilogue ----
#pragma unroll
    for (int mi = 0; mi < 8; ++mi)
#pragma unroll
        for (int ni = 0; ni < 4; ++ni)
#pragma unroll
            for (int j = 0; j < 4; ++j) {
                const int row = m0 + wr * 128 + mi * 16 + q * 4 + j;
                const int col = n0 + wc * 64 + ni * 16 + l15;
                const size_t idx = (size_t)row * N + col;
                const float av = acc[mi][ni][j];
                if (MODE == 1) {
                    outB[idx] = f2bf(av / (1.f + __expf(-av)));
                } else if (MODE == 2) {
                    outF[idx] = res[idx] + av;
                } else if (MODE == 3) {
                    float tt = fmaxf(av, 0.f);
                    outB[idx] = f2bf(tt * tt);
                } else if (MODE == 4) {
                    outB[idx] = f2bf(1.f / (1.f + __expf(-av)));
                } else if (MODE == 5) {
                    outF[idx] = res[idx] + bf2f(sg[idx]) * av;
                } else {
                    outB[idx] = f2bf(av);
                }
            }
}

// ---------------- WKV5: chunked linear attention + fused GroupNorm*gate ------
__global__ __launch_bounds__(256)
void wkv_kernel(const unsigned short* __restrict__ r, const unsigned short* __restrict__ k,
                const unsigned short* __restrict__ v, const unsigned short* __restrict__ g,
                const float* __restrict__ decay, const float* __restrict__ faaaa,
                const float* __restrict__ lnxw, const float* __restrict__ lnxb,
                unsigned short* __restrict__ ao) {
    __shared__ unsigned short rp[64 * 72], km[64 * 72], kdT[64 * 72];
    __shared__ unsigned short VT[64 * 72], Abf[64 * 72], ScT[64 * 72], Gsh[64 * 72];
    __shared__ float Dt[64];
    const int tid = threadIdx.x;
    const int bh = blockIdx.x, b = bh >> 4, h = bh & 15;
    const int tr = tid >> 2, g4 = tid & 3, i0 = g4 * 16;
    const int wv = tid >> 6, lane = tid & 63, l15 = lane & 15, q = lane >> 4;
    const float LOG2E = 1.44269504088896340736f;

    float l2w[16], uu[16];
#pragma unroll
    for (int ii = 0; ii < 16; ++ii) {
        l2w[ii] = -__expf(decay[h * Nq + i0 + ii]) * LOG2E;
        uu[ii] = faaaa[h * Nq + i0 + ii];
    }
    float ewL[4];
#pragma unroll
    for (int jr = 0; jr < 4; ++jr) {
        float lw = -__expf(decay[h * Nq + 16 * wv + q * 4 + jr]) * LOG2E;
        ewL[jr] = exp2f(64.f * lw);
    }
    const int colbase = h * Nq;
    float lwj[4], lbj[4];
#pragma unroll
    for (int nt = 0; nt < 4; ++nt) {
        lwj[nt] = lnxw[colbase + 16 * nt + l15];
        lbj[nt] = lnxb[colbase + 16 * nt + l15];
    }
    f32x4 S[4];
#pragma unroll
    for (int nt = 0; nt < 4; ++nt) S[nt] = {0.f, 0.f, 0.f, 0.f};
    for (int idx = tid; idx < 64 * 72; idx += 256) ScT[idx] = 0;
    __syncthreads();

    const size_t rowbase = (size_t)b * Tq;

    for (int c = 0; c < 32; ++c) {
        const size_t grow = (rowbase + c * 64 + tr) * Cq + colbase + i0;
        unsigned short rs_[16], ks_[16], vs_[16];
        *(uint4*)&rs_[0] = *(const uint4*)(r + grow);
        *(uint4*)&rs_[8] = *(const uint4*)(r + grow + 8);
        *(uint4*)&ks_[0] = *(const uint4*)(k + grow);
        *(uint4*)&ks_[8] = *(const uint4*)(k + grow + 8);
        *(uint4*)&vs_[0] = *(const uint4*)(v + grow);
        *(uint4*)&vs_[8] = *(const uint4*)(v + grow + 8);
        *(uint4*)&Gsh[tr * 72 + i0] = *(const uint4*)(g + grow);
        *(uint4*)&Gsh[tr * 72 + i0 + 8] = *(const uint4*)(g + grow + 8);
        float pd = 0.f;
        const float ftr = (float)tr;
#pragma unroll
        for (int ii = 0; ii < 16; ++ii) {
            float rf = bf2f(rs_[ii]), kf = bf2f(ks_[ii]);
            rp[tr * 72 + i0 + ii] = f2bf(rf * exp2f(ftr * l2w[ii]));
            km[tr * 72 + i0 + ii] = f2bf(kf * exp2f(-(ftr + 1.f) * l2w[ii]));
            kdT[(i0 + ii) * 72 + tr] = f2bf(kf * exp2f((63.f - ftr) * l2w[ii]));
            VT[(i0 + ii) * 72 + tr] = vs_[ii];
            pd += rf * uu[ii] * kf;
        }
        pd += __shfl_xor(pd, 1);
        pd += __shfl_xor(pd, 2);
        if (g4 == 0) Dt[tr] = pd;
        __syncthreads();

        f32x4 accA[4];
#pragma unroll
        for (int nt = 0; nt < 4; ++nt) accA[nt] = {0.f, 0.f, 0.f, 0.f};
#pragma unroll
        for (int ks = 0; ks < 2; ++ks) {
            bf8v a = *(const bf8v*)&rp[(16 * wv + l15) * 72 + ks * 32 + q * 8];
#pragma unroll
            for (int nt = 0; nt < 4; ++nt) {
                bf8v bbv = *(const bf8v*)&km[(16 * nt + l15) * 72 + ks * 32 + q * 8];
                accA[nt] = __builtin_amdgcn_mfma_f32_16x16x32_bf16(a, bbv, accA[nt], 0, 0, 0);
            }
        }
#pragma unroll
        for (int nt = 0; nt < 4; ++nt)
#pragma unroll
            for (int jr = 0; jr < 4; ++jr) {
                const int t = 16 * wv + q * 4 + jr, s = 16 * nt + l15;
                const float a = accA[nt][jr];
                const float val = (s < t) ? a : ((s == t) ? Dt[t] : 0.f);
                Abf[t * 72 + s] = f2bf(val);
            }

        f32x4 accY[4];
#pragma unroll
        for (int nt = 0; nt < 4; ++nt) accY[nt] = {0.f, 0.f, 0.f, 0.f};
#pragma unroll
        for (int ks = 0; ks < 2; ++ks) {
            bf8v a = *(const bf8v*)&Abf[(16 * wv + l15) * 72 + ks * 32 + q * 8];
#pragma unroll
            for (int nt = 0; nt < 4; ++nt) {
                bf8v bbv = *(const bf8v*)&VT[(16 * nt + l15) * 72 + ks * 32 + q * 8];
                accY[nt] = __builtin_amdgcn_mfma_f32_16x16x32_bf16(a, bbv, accY[nt], 0, 0, 0);
            }
        }
#pragma unroll
        for (int ks = 0; ks < 2; ++ks) {
            bf8v a = *(const bf8v*)&rp[(16 * wv + l15) * 72 + ks * 32 + q * 8];
#pragma unroll
            for (int nt = 0; nt < 4; ++nt) {
                bf8v bbv = *(const bf8v*)&ScT[(16 * nt + l15) * 72 + ks * 32 + q * 8];
                accY[nt] = __builtin_amdgcn_mfma_f32_16x16x32_bf16(a, bbv, accY[nt], 0, 0, 0);
            }
        }

        float sum_[4] = {0.f, 0.f, 0.f, 0.f}, sq_[4] = {0.f, 0.f, 0.f, 0.f};
#pragma unroll
        for (int nt = 0; nt < 4; ++nt)
#pragma unroll
            for (int jr = 0; jr < 4; ++jr) {
                float yv = accY[nt][jr] * 0.125f;
                accY[nt][jr] = yv;
                sum_[jr] += yv;
                sq_[jr] += yv * yv;
            }
#pragma unroll
        for (int m = 1; m < 16; m <<= 1)
#pragma unroll
            for (int jr = 0; jr < 4; ++jr) {
                sum_[jr] += __shfl_xor(sum_[jr], m);
                sq_[jr] += __shfl_xor(sq_[jr], m);
            }
        float mu_[4], rstd_[4];
#pragma unroll
        for (int jr = 0; jr < 4; ++jr) {
            mu_[jr] = sum_[jr] * (1.f / Nq);
            rstd_[jr] = rsqrtf(sq_[jr] * (1.f / Nq) - mu_[jr] * mu_[jr] + EPSq);
        }
#pragma unroll
        for (int nt = 0; nt < 4; ++nt)
#pragma unroll
            for (int jr = 0; jr < 4; ++jr) {
                const int t = 16 * wv + q * 4 + jr;
                const float gate = bf2f(Gsh[t * 72 + 16 * nt + l15]);
                const float val = (accY[nt][jr] - mu_[jr]) * rstd_[jr] * lwj[nt] + lbj[nt];
                ao[(rowbase + c * 64 + t) * Cq + colbase + 16 * nt + l15] = f2bf(val * gate);
            }

        f32x4 accU[4];
#pragma unroll
        for (int nt = 0; nt < 4; ++nt) accU[nt] = {0.f, 0.f, 0.f, 0.f};
#pragma unroll
        for (int ks = 0; ks < 2; ++ks) {
            bf8v a = *(const bf8v*)&kdT[(16 * wv + l15) * 72 + ks * 32 + q * 8];
#pragma unroll
            for (int nt = 0; nt < 4; ++nt) {
                bf8v bbv = *(const bf8v*)&VT[(16 * nt + l15) * 72 + ks * 32 + q * 8];
                accU[nt] = __builtin_amdgcn_mfma_f32_16x16x32_bf16(a, bbv, accU[nt], 0, 0, 0);
            }
        }
        __syncthreads();
#pragma unroll
        for (int nt = 0; nt < 4; ++nt) {
#pragma unroll
            for (int jr = 0; jr < 4; ++jr)
                S[nt][jr] = ewL[jr] * S[nt][jr] + accU[nt][jr];
            ushort4 sc;
            sc.x = f2bf(S[nt][0]); sc.y = f2bf(S[nt][1]);
            sc.z = f2bf(S[nt][2]); sc.w = f2bf(S[nt][3]);
            *(ushort4*)&ScT[(16 * nt + l15) * 72 + 16 * wv + q * 4] = sc;
        }
        __syncthreads();
    }
}

// ---------------- launcher ----------------
extern "C" void kernel_launch(void* const* d_in, const int* in_sizes, int n_in,
                              void* d_out, int out_size, void* d_ws, size_t ws_size,
                              hipStream_t stream) {
    const float* x     = (const float*)d_in[0];
    const float* ln0w  = (const float*)d_in[1];
    const float* ln0b  = (const float*)d_in[2];
    const float* ln1w  = (const float*)d_in[3];
    const float* ln1b  = (const float*)d_in[4];
    const float* ln2w  = (const float*)d_in[5];
    const float* ln2b  = (const float*)d_in[6];
    const float* atmk  = (const float*)d_in[7];
    const float* atmv  = (const float*)d_in[8];
    const float* atmr  = (const float*)d_in[9];
    const float* atmg  = (const float*)d_in[10];
    const float* decay = (const float*)d_in[11];
    const float* faaaa = (const float*)d_in[12];
    const float* aWr   = (const float*)d_in[13];
    const float* aWk   = (const float*)d_in[14];
    const float* aWv   = (const float*)d_in[15];
    const float* aWg   = (const float*)d_in[16];
    const float* aWo   = (const float*)d_in[17];
    const float* lnxw  = (const float*)d_in[18];
    const float* lnxb  = (const float*)d_in[19];
    const float* ftmk  = (const float*)d_in[20];
    const float* ftmr  = (const float*)d_in[21];
    const float* fWk   = (const float*)d_in[22];
    const float* fWr   = (const float*)d_in[23];
    const float* fWv   = (const float*)d_in[24];

    const size_t MB = 1024ull * 1024ull;
    const size_t WS_NEEDED = 250 * MB;
    dim3 blk(256);

    if (ws_size < WS_NEEDED) {
        diag_kernel<<<out_size / 1024, blk, 0, stream>>>((float*)d_out,
            1000.f + (float)((double)ws_size / (double)MB));
        return;
    }

    char* ws = (char*)d_ws;
    unsigned short* WR  = (unsigned short*)(ws + 0 * MB);
    unsigned short* WK  = (unsigned short*)(ws + 2 * MB);
    unsigned short* WV  = (unsigned short*)(ws + 4 * MB);
    unsigned short* WG  = (unsigned short*)(ws + 6 * MB);
    unsigned short* WO  = (unsigned short*)(ws + 8 * MB);
    unsigned short* FWK = (unsigned short*)(ws + 10 * MB);
    unsigned short* FWR = (unsigned short*)(ws + 17 * MB);
    unsigned short* FWV = (unsigned short*)(ws + 19 * MB);
    unsigned short* XN  = (unsigned short*)(ws + 26 * MB);
    unsigned short* MXR = (unsigned short*)(ws + 58 * MB);
    unsigned short* MXK = (unsigned short*)(ws + 90 * MB);
    unsigned short* MXV = (unsigned short*)(ws + 122 * MB);
    unsigned short* MXG = (unsigned short*)(ws + 154 * MB);
    unsigned short* Rb  = (unsigned short*)(ws + 186 * MB);
    unsigned short* Kb  = (unsigned short*)(ws + 58 * MB);
    unsigned short* Vb  = (unsigned short*)(ws + 90 * MB);
    unsigned short* Gb  = (unsigned short*)(ws + 122 * MB);
    unsigned short* AO  = (unsigned short*)(ws + 154 * MB);
    unsigned short* XK2 = (unsigned short*)(ws + 58 * MB);
    unsigned short* XR2 = (unsigned short*)(ws + 90 * MB);
    unsigned short* KF  = (unsigned short*)(ws + 122 * MB);
    unsigned short* SRb = (unsigned short*)(ws + 26 * MB);
    float*          X0  = (float*)d_out;

    const int NTOK = Bq * Tq;  // 16384
    dim3 blk512(512);
    const int gsq = (NTOK / 256) * (Cq / 256);    // 64*4  = 256 blocks
    const int gup = (NTOK / 256) * (FFNq / 256);  // 64*14 = 896 blocks

    f2bf_all_kernel<<<13312, blk, 0, stream>>>(aWr, aWk, aWv, aWg, aWo, fWk, fWr, fWv,
                                               WR, WK, WV, WG, WO, FWK, FWR, FWV);

    ln01_kernel<<<NTOK, blk, 0, stream>>>(x, ln0w, ln0b, ln1w, ln1b, X0, XN);

    mix4_kernel<<<NTOK, blk, 0, stream>>>(XN, atmr, atmk, atmv, atmg,
                                          (ushort4*)MXR, (ushort4*)MXK,
                                          (ushort4*)MXV, (ushort4*)MXG);

    gemm256<6><<<gsq, blk512, 0, stream>>>(MXR, WR, Cq, Cq, nullptr, Rb, nullptr, nullptr);
    gemm256<6><<<gsq, blk512, 0, stream>>>(MXK, WK, Cq, Cq, nullptr, Kb, nullptr, nullptr);
    gemm256<6><<<gsq, blk512, 0, stream>>>(MXV, WV, Cq, Cq, nullptr, Vb, nullptr, nullptr);
    gemm256<1><<<gsq, blk512, 0, stream>>>(MXG, WG, Cq, Cq, nullptr, Gb, nullptr, nullptr);

    wkv_kernel<<<Bq * Hq, blk, 0, stream>>>(Rb, Kb, Vb, Gb, decay, faaaa, lnxw, lnxb, AO);
    gemm256<2><<<gsq, blk512, 0, stream>>>(AO, WO, Cq, Cq, X0, nullptr, X0, nullptr);

    ln_kernel<<<NTOK, blk, 0, stream>>>(X0, ln2w, ln2b, XN);
    mix2_kernel<<<NTOK, blk, 0, stream>>>(XN, ftmk, ftmr, (ushort4*)XK2, (ushort4*)XR2);
    gemm256<3><<<gup, blk512, 0, stream>>>(XK2, FWK, Cq, FFNq, nullptr, KF, nullptr, nullptr);
    gemm256<4><<<gsq, blk512, 0, stream>>>(XR2, FWR, Cq, Cq, nullptr, SRb, nullptr, nullptr);
    gemm256<5><<<gsq, blk512, 0, stream>>>(KF, FWV, FFNq, Cq, X0, nullptr, X0, SRb);
}

// Round 6
// 943.664 us; speedup vs baseline: 1.0598x; 1.0210x over previous
//
#include <hip/hip_runtime.h>

#define Bq 8
#define Tq 2048
#define Cq 1024
#define Hq 16
#define Nq 64
#define FFNq 3584
#define EPSq 1e-5f

typedef __bf16 bf8v __attribute__((ext_vector_type(8)));
typedef float f32x4 __attribute__((ext_vector_type(4)));

typedef __attribute__((address_space(1))) const unsigned int GU;
typedef __attribute__((address_space(3))) unsigned int LU;

__device__ __forceinline__ void gload16(const unsigned short* g, unsigned short* l) {
    __builtin_amdgcn_global_load_lds((GU*)g, (LU*)l, 16, 0, 0);
}

__device__ __forceinline__ unsigned short f2bf(float f) {
    unsigned u = __float_as_uint(f);
    u += 0x7fffu + ((u >> 16) & 1u);   // round-to-nearest-even
    return (unsigned short)(u >> 16);
}
__device__ __forceinline__ float bf2f(unsigned short h) {
    return __uint_as_float(((unsigned)h) << 16);
}

// ---------------- diagnostic fill (ws too small) ----------------
__global__ __launch_bounds__(256)
void diag_kernel(float* __restrict__ out, float val) {
    int i = (blockIdx.x * 256 + threadIdx.x) * 4;
    float4 v = make_float4(val, val, val, val);
    *(float4*)(out + i) = v;
}

// ---------------- fp32 -> bf16 conversion, all 8 weights in one launch -------
__global__ __launch_bounds__(256)
void f2bf_all_kernel(const float* __restrict__ s0, const float* __restrict__ s1,
                     const float* __restrict__ s2, const float* __restrict__ s3,
                     const float* __restrict__ s4, const float* __restrict__ s5,
                     const float* __restrict__ s6, const float* __restrict__ s7,
                     unsigned short* __restrict__ d0, unsigned short* __restrict__ d1,
                     unsigned short* __restrict__ d2, unsigned short* __restrict__ d3,
                     unsigned short* __restrict__ d4, unsigned short* __restrict__ d5,
                     unsigned short* __restrict__ d6, unsigned short* __restrict__ d7) {
    int b = blockIdx.x;
    const float* src; unsigned short* dst;
    if      (b < 1024)  { src = s0; dst = d0; }
    else if (b < 2048)  { src = s1; dst = d1; b -= 1024; }
    else if (b < 3072)  { src = s2; dst = d2; b -= 2048; }
    else if (b < 4096)  { src = s3; dst = d3; b -= 3072; }
    else if (b < 5120)  { src = s4; dst = d4; b -= 4096; }
    else if (b < 8704)  { src = s5; dst = d5; b -= 5120; }
    else if (b < 9728)  { src = s6; dst = d6; b -= 8704; }
    else                { src = s7; dst = d7; b -= 9728; }
    int i = (b * 256 + threadIdx.x) * 4;
    float4 v = *(const float4*)(src + i);
    ushort4 o;
    o.x = f2bf(v.x); o.y = f2bf(v.y); o.z = f2bf(v.z); o.w = f2bf(v.w);
    *(ushort4*)(dst + i) = o;
}

// ---------------- block reduction helper (256 threads) ----------------
__device__ __forceinline__ void blockred2(float& a, float& b, float* sm) {
#pragma unroll
    for (int m = 1; m < 64; m <<= 1) { a += __shfl_xor(a, m); b += __shfl_xor(b, m); }
    const int w = threadIdx.x >> 6;
    __syncthreads();
    if ((threadIdx.x & 63) == 0) { sm[w] = a; sm[4 + w] = b; }
    __syncthreads();
    a = sm[0] + sm[1] + sm[2] + sm[3];
    b = sm[4] + sm[5] + sm[6] + sm[7];
}

// ---------------- ln0 + ln1 fused: x -> x0 (fp32), xn (bf16) ----------------
__global__ __launch_bounds__(256)
void ln01_kernel(const float* __restrict__ x,
                 const float* __restrict__ w0, const float* __restrict__ b0,
                 const float* __restrict__ w1, const float* __restrict__ b1,
                 float* __restrict__ x0, unsigned short* __restrict__ xn) {
    __shared__ float sm[8];
    const int tok = blockIdx.x, tid = threadIdx.x, c = tid * 4;
    const size_t base = (size_t)tok * Cq + c;
    float4 v = *(const float4*)(x + base);
    float s = v.x + v.y + v.z + v.w;
    float ss = v.x * v.x + v.y * v.y + v.z * v.z + v.w * v.w;
    blockred2(s, ss, sm);
    float mu = s * (1.f / Cq);
    float rstd = rsqrtf(ss * (1.f / Cq) - mu * mu + EPSq);
    float4 wv = *(const float4*)(w0 + c), bv = *(const float4*)(b0 + c);
    float4 e;
    e.x = (v.x - mu) * rstd * wv.x + bv.x;
    e.y = (v.y - mu) * rstd * wv.y + bv.y;
    e.z = (v.z - mu) * rstd * wv.z + bv.z;
    e.w = (v.w - mu) * rstd * wv.w + bv.w;
    *(float4*)(x0 + base) = e;
    s = e.x + e.y + e.z + e.w;
    ss = e.x * e.x + e.y * e.y + e.z * e.z + e.w * e.w;
    blockred2(s, ss, sm);
    mu = s * (1.f / Cq);
    rstd = rsqrtf(ss * (1.f / Cq) - mu * mu + EPSq);
    wv = *(const float4*)(w1 + c); bv = *(const float4*)(b1 + c);
    ushort4 o;
    o.x = f2bf((e.x - mu) * rstd * wv.x + bv.x);
    o.y = f2bf((e.y - mu) * rstd * wv.y + bv.y);
    o.z = f2bf((e.z - mu) * rstd * wv.z + bv.z);
    o.w = f2bf((e.w - mu) * rstd * wv.w + bv.w);
    *(ushort4*)(xn + base) = o;
}

// ---------------- single layernorm (ln2): fp32 in -> bf16 out ----------------
__global__ __launch_bounds__(256)
void ln_kernel(const float* __restrict__ x, const float* __restrict__ w,
               const float* __restrict__ b, unsigned short* __restrict__ out) {
    __shared__ float sm[8];
    const int tok = blockIdx.x, tid = threadIdx.x, c = tid * 4;
    const size_t base = (size_t)tok * Cq + c;
    float4 v = *(const float4*)(x + base);
    float s = v.x + v.y + v.z + v.w;
    float ss = v.x * v.x + v.y * v.y + v.z * v.z + v.w * v.w;
    blockred2(s, ss, sm);
    float mu = s * (1.f / Cq);
    float rstd = rsqrtf(ss * (1.f / Cq) - mu * mu + EPSq);
    float4 wv = *(const float4*)(w + c), bv = *(const float4*)(b + c);
    ushort4 o;
    o.x = f2bf((v.x - mu) * rstd * wv.x + bv.x);
    o.y = f2bf((v.y - mu) * rstd * wv.y + bv.y);
    o.z = f2bf((v.z - mu) * rstd * wv.z + bv.z);
    o.w = f2bf((v.w - mu) * rstd * wv.w + bv.w);
    *(ushort4*)(out + base) = o;
}

// ---------------- token-shift: 4 mixes in one pass (time-mix) ----------------
__device__ __forceinline__ ushort4 mixpack(float ax, float ay, float az, float aw,
                                           float px, float py, float pz, float pw,
                                           const float4& m) {
    ushort4 o;
    o.x = f2bf(px + m.x * (ax - px));
    o.y = f2bf(py + m.y * (ay - py));
    o.z = f2bf(pz + m.z * (az - pz));
    o.w = f2bf(pw + m.w * (aw - pw));
    return o;
}

__global__ __launch_bounds__(256)
void mix4_kernel(const unsigned short* __restrict__ xn,
                 const float* __restrict__ tmr, const float* __restrict__ tmk,
                 const float* __restrict__ tmv, const float* __restrict__ tmg,
                 ushort4* __restrict__ outR, ushort4* __restrict__ outK,
                 ushort4* __restrict__ outV, ushort4* __restrict__ outG) {
    const int tok = blockIdx.x, tid = threadIdx.x, c = tid * 4;
    const int t = tok & (Tq - 1);
    const size_t base = (size_t)tok * Cq + c;
    ushort4 a = *(const ushort4*)(xn + base);
    ushort4 p = make_ushort4(0, 0, 0, 0);
    if (t) p = *(const ushort4*)(xn + base - Cq);
    float ax = bf2f(a.x), ay = bf2f(a.y), az = bf2f(a.z), aw = bf2f(a.w);
    float px = bf2f(p.x), py = bf2f(p.y), pz = bf2f(p.z), pw = bf2f(p.w);
    const size_t b4 = (size_t)tok * 256 + tid;
    outR[b4] = mixpack(ax, ay, az, aw, px, py, pz, pw, *(const float4*)(tmr + c));
    outK[b4] = mixpack(ax, ay, az, aw, px, py, pz, pw, *(const float4*)(tmk + c));
    outV[b4] = mixpack(ax, ay, az, aw, px, py, pz, pw, *(const float4*)(tmv + c));
    outG[b4] = mixpack(ax, ay, az, aw, px, py, pz, pw, *(const float4*)(tmg + c));
}

// ---------------- token-shift: 2 mixes in one pass (channel-mix) -------------
__global__ __launch_bounds__(256)
void mix2_kernel(const unsigned short* __restrict__ xn,
                 const float* __restrict__ tmk, const float* __restrict__ tmr,
                 ushort4* __restrict__ outK, ushort4* __restrict__ outR) {
    const int tok = blockIdx.x, tid = threadIdx.x, c = tid * 4;
    const int t = tok & (Tq - 1);
    const size_t base = (size_t)tok * Cq + c;
    ushort4 a = *(const ushort4*)(xn + base);
    ushort4 p = make_ushort4(0, 0, 0, 0);
    if (t) p = *(const ushort4*)(xn + base - Cq);
    float ax = bf2f(a.x), ay = bf2f(a.y), az = bf2f(a.z), aw = bf2f(a.w);
    float px = bf2f(p.x), py = bf2f(p.y), pz = bf2f(p.z), pw = bf2f(p.w);
    const size_t b4 = (size_t)tok * 256 + tid;
    outK[b4] = mixpack(ax, ay, az, aw, px, py, pz, pw, *(const float4*)(tmk + c));
    outR[b4] = mixpack(ax, ay, az, aw, px, py, pz, pw, *(const float4*)(tmr + c));
}

// ---------------- 256x128 TLP-first bf16 MFMA GEMM ---------------------------
// (R5 resubmit -- container-level infra failure, kernel audited sound.)
// out[m,n] = sum_k A[m,k]*W[n,k].  512 threads = 8 waves (4M x 2N), per-wave
// 64x64 output (acc[4][4] = 64 VGPR).  BK=32; LDS ring of 3 slots x 24KB
// (A [256][32] + B [128][32]) = 72 KiB -> TWO blocks/CU (16 waves/CU).
// Rationale (R4 post-mortem): schedule variants at 1 block/CU all hit the same
// ~163 us; the kernel is memory-LATENCY-bound with zero TLP (one barrier
// domain).  Two independent blocks/CU restore m97's proven latency hiding
// (R0: 40 B/cyc/CU staged vs R1-R4: 21.5) while counted vmcnt keeps a 2-step
// in-block pipeline.  __launch_bounds__(512,4) forces <=128 VGPR so both
// blocks stay resident.
// Schedule per K-step k: issue 3 gload_lds for slot (k+2)%3 FIRST; 8x
// ds_read_b128 (frags for k); 16 MFMA (compiler inserts fine lgkmcnt);
// s_waitcnt vmcnt(3) (certifies k+1; outstanding = k+2's 3 loads; never 0
// until tail); s_barrier.  WAR: slot (k+2)%3 was last read at step k-1,
// whose reads completed before its end barrier.
// Swizzle: LDS(row,u) holds global chunk u^(row&3); frag reads use chunk
// q^(l15&3) -> balanced banks; staging source pre-swizzled, dest linear.
// MODE: 1 silu->bf16; 2 res+acc->fp32; 3 relu^2->bf16; 4 sigmoid->bf16;
//       5 res+bf2f(sg)*acc->fp32; 6 plain->bf16.  Requires K%32==0, K>=96,
//       M%256==0, N%128==0, grid%8==0 (all call sites satisfy).
template<int MODE>
__global__ __launch_bounds__(512, 4)
void gemm128(const unsigned short* __restrict__ A, const unsigned short* __restrict__ W,
             int K, int N, float* __restrict__ outF, unsigned short* __restrict__ outB,
             const float* __restrict__ res, const unsigned short* __restrict__ sg) {
    __shared__ unsigned short lds[3][12288];  // per slot: A elems 0..8191, B 8192..12287
    const int tid = threadIdx.x;
    const int wid = tid >> 6, lane = tid & 63;
    const int wr = wid >> 1, wc = wid & 1;       // wave grid 4 (M) x 2 (N)
    const int l15 = lane & 15, q = lane >> 4;

    // T1: bijective XCD swizzle (grid % 8 == 0), m-major over nn n-blocks
    const int nn = N >> 7;
    const int q8 = gridDim.x >> 3;
    const int bid = blockIdx.x;
    const int swz = (bid & 7) * q8 + (bid >> 3);
    const int m0 = (swz / nn) * 256;
    const int n0 = (swz % nn) * 128;

    // staging: thread covers A rows (tid>>2), 128+(tid>>2) and B row (tid>>2);
    // source chunk pre-swizzled: (tid&3) ^ ((tid>>2)&3).
    const int srow = tid >> 2;
    const int scol = ((tid & 3) ^ ((tid >> 2) & 3)) * 8;
    const unsigned short* aS0 = A + (size_t)(m0 + srow) * K + scol;
    const unsigned short* aS1 = A + (size_t)(m0 + 128 + srow) * K + scol;
    const unsigned short* wS  = W + (size_t)(n0 + srow) * K + scol;

    // fragment read offsets (elems): chunk = q ^ (row&3), row&3 == l15&3
    const int fco = (q ^ (l15 & 3)) * 8;
    const int aOff = (wr * 64 + l15) * 32 + fco;          // + mi*512
    const int bOff = 8192 + (wc * 64 + l15) * 32 + fco;   // + ni*512

    f32x4 acc[4][4];
#pragma unroll
    for (int mi = 0; mi < 4; ++mi)
#pragma unroll
        for (int ni = 0; ni < 4; ++ni)
            acc[mi][ni] = {0.f, 0.f, 0.f, 0.f};

    const int NJ = K >> 5;

    // prologue: stage slots 0,1 (k=0,1) = 6 loads; vmcnt(3) certifies k=0
#pragma unroll
    for (int j = 0; j < 2; ++j) {
        gload16(aS0 + j * 32, &lds[j][tid * 8]);
        gload16(aS1 + j * 32, &lds[j][4096 + tid * 8]);
        gload16(wS  + j * 32, &lds[j][8192 + tid * 8]);
    }
    asm volatile("s_waitcnt vmcnt(3)" ::: "memory");
    __builtin_amdgcn_s_barrier();

    unsigned short* L0 = &lds[0][0];
    unsigned short* L1 = &lds[1][0];
    unsigned short* L2 = &lds[2][0];

    for (int k = 0; k < NJ; ++k) {
        // issue next-next staging first (long-latency)
        if (k + 2 < NJ) {
            gload16(aS0 + (k + 2) * 32, L2 + tid * 8);
            gload16(aS1 + (k + 2) * 32, L2 + 4096 + tid * 8);
            gload16(wS  + (k + 2) * 32, L2 + 8192 + tid * 8);
        }
        bf8v a[4], b[4];
#pragma unroll
        for (int i = 0; i < 4; ++i) a[i] = *(const bf8v*)&L0[aOff + i * 512];
#pragma unroll
        for (int i = 0; i < 4; ++i) b[i] = *(const bf8v*)&L0[bOff + i * 512];
        __builtin_amdgcn_s_setprio(1);
#pragma unroll
        for (int mi = 0; mi < 4; ++mi)
#pragma unroll
            for (int ni = 0; ni < 4; ++ni)
                acc[mi][ni] = __builtin_amdgcn_mfma_f32_16x16x32_bf16(a[mi], b[ni], acc[mi][ni], 0, 0, 0);
        __builtin_amdgcn_s_setprio(0);
        if (k < NJ - 2) {
            asm volatile("s_waitcnt vmcnt(3)" ::: "memory");
            __builtin_amdgcn_s_barrier();
        } else if (k == NJ - 2) {
            asm volatile("s_waitcnt vmcnt(0)" ::: "memory");
            __builtin_amdgcn_s_barrier();
        }
        unsigned short* t0 = L0; L0 = L1; L1 = L2; L2 = t0;
    }

    // ---- epilogue ----
#pragma unroll
    for (int mi = 0; mi < 4; ++mi)
#pragma unroll
        for (int ni = 0; ni < 4; ++ni)
#pragma unroll
            for (int j = 0; j < 4; ++j) {
                const int row = m0 + wr * 64 + mi * 16 + q * 4 + j;
                const int col = n0 + wc * 64 + ni * 16 + l15;
                const size_t idx = (size_t)row * N + col;
                const float av = acc[mi][ni][j];
                if (MODE == 1) {
                    outB[idx] = f2bf(av / (1.f + __expf(-av)));
                } else if (MODE == 2) {
                    outF[idx] = res[idx] + av;
                } else if (MODE == 3) {
                    float tt = fmaxf(av, 0.f);
                    outB[idx] = f2bf(tt * tt);
                } else if (MODE == 4) {
                    outB[idx] = f2bf(1.f / (1.f + __expf(-av)));
                } else if (MODE == 5) {
                    outF[idx] = res[idx] + bf2f(sg[idx]) * av;
                } else {
                    outB[idx] = f2bf(av);
                }
            }
}

// ---------------- WKV5: chunked linear attention + fused GroupNorm*gate ------
__global__ __launch_bounds__(256)
void wkv_kernel(const unsigned short* __restrict__ r, const unsigned short* __restrict__ k,
                const unsigned short* __restrict__ v, const unsigned short* __restrict__ g,
                const float* __restrict__ decay, const float* __restrict__ faaaa,
                const float* __restrict__ lnxw, const float* __restrict__ lnxb,
                unsigned short* __restrict__ ao) {
    __shared__ unsigned short rp[64 * 72], km[64 * 72], kdT[64 * 72];
    __shared__ unsigned short VT[64 * 72], Abf[64 * 72], ScT[64 * 72], Gsh[64 * 72];
    __shared__ float Dt[64];
    const int tid = threadIdx.x;
    const int bh = blockIdx.x, b = bh >> 4, h = bh & 15;
    const int tr = tid >> 2, g4 = tid & 3, i0 = g4 * 16;
    const int wv = tid >> 6, lane = tid & 63, l15 = lane & 15, q = lane >> 4;
    const float LOG2E = 1.44269504088896340736f;

    float l2w[16], uu[16];
#pragma unroll
    for (int ii = 0; ii < 16; ++ii) {
        l2w[ii] = -__expf(decay[h * Nq + i0 + ii]) * LOG2E;
        uu[ii] = faaaa[h * Nq + i0 + ii];
    }
    float ewL[4];
#pragma unroll
    for (int jr = 0; jr < 4; ++jr) {
        float lw = -__expf(decay[h * Nq + 16 * wv + q * 4 + jr]) * LOG2E;
        ewL[jr] = exp2f(64.f * lw);
    }
    const int colbase = h * Nq;
    float lwj[4], lbj[4];
#pragma unroll
    for (int nt = 0; nt < 4; ++nt) {
        lwj[nt] = lnxw[colbase + 16 * nt + l15];
        lbj[nt] = lnxb[colbase + 16 * nt + l15];
    }
    f32x4 S[4];
#pragma unroll
    for (int nt = 0; nt < 4; ++nt) S[nt] = {0.f, 0.f, 0.f, 0.f};
    for (int idx = tid; idx < 64 * 72; idx += 256) ScT[idx] = 0;
    __syncthreads();

    const size_t rowbase = (size_t)b * Tq;

    for (int c = 0; c < 32; ++c) {
        const size_t grow = (rowbase + c * 64 + tr) * Cq + colbase + i0;
        unsigned short rs_[16], ks_[16], vs_[16];
        *(uint4*)&rs_[0] = *(const uint4*)(r + grow);
        *(uint4*)&rs_[8] = *(const uint4*)(r + grow + 8);
        *(uint4*)&ks_[0] = *(const uint4*)(k + grow);
        *(uint4*)&ks_[8] = *(const uint4*)(k + grow + 8);
        *(uint4*)&vs_[0] = *(const uint4*)(v + grow);
        *(uint4*)&vs_[8] = *(const uint4*)(v + grow + 8);
        *(uint4*)&Gsh[tr * 72 + i0] = *(const uint4*)(g + grow);
        *(uint4*)&Gsh[tr * 72 + i0 + 8] = *(const uint4*)(g + grow + 8);
        float pd = 0.f;
        const float ftr = (float)tr;
#pragma unroll
        for (int ii = 0; ii < 16; ++ii) {
            float rf = bf2f(rs_[ii]), kf = bf2f(ks_[ii]);
            rp[tr * 72 + i0 + ii] = f2bf(rf * exp2f(ftr * l2w[ii]));
            km[tr * 72 + i0 + ii] = f2bf(kf * exp2f(-(ftr + 1.f) * l2w[ii]));
            kdT[(i0 + ii) * 72 + tr] = f2bf(kf * exp2f((63.f - ftr) * l2w[ii]));
            VT[(i0 + ii) * 72 + tr] = vs_[ii];
            pd += rf * uu[ii] * kf;
        }
        pd += __shfl_xor(pd, 1);
        pd += __shfl_xor(pd, 2);
        if (g4 == 0) Dt[tr] = pd;
        __syncthreads();

        f32x4 accA[4];
#pragma unroll
        for (int nt = 0; nt < 4; ++nt) accA[nt] = {0.f, 0.f, 0.f, 0.f};
#pragma unroll
        for (int ks = 0; ks < 2; ++ks) {
            bf8v a = *(const bf8v*)&rp[(16 * wv + l15) * 72 + ks * 32 + q * 8];
#pragma unroll
            for (int nt = 0; nt < 4; ++nt) {
                bf8v bbv = *(const bf8v*)&km[(16 * nt + l15) * 72 + ks * 32 + q * 8];
                accA[nt] = __builtin_amdgcn_mfma_f32_16x16x32_bf16(a, bbv, accA[nt], 0, 0, 0);
            }
        }
#pragma unroll
        for (int nt = 0; nt < 4; ++nt)
#pragma unroll
            for (int jr = 0; jr < 4; ++jr) {
                const int t = 16 * wv + q * 4 + jr, s = 16 * nt + l15;
                const float a = accA[nt][jr];
                const float val = (s < t) ? a : ((s == t) ? Dt[t] : 0.f);
                Abf[t * 72 + s] = f2bf(val);
            }

        f32x4 accY[4];
#pragma unroll
        for (int nt = 0; nt < 4; ++nt) accY[nt] = {0.f, 0.f, 0.f, 0.f};
#pragma unroll
        for (int ks = 0; ks < 2; ++ks) {
            bf8v a = *(const bf8v*)&Abf[(16 * wv + l15) * 72 + ks * 32 + q * 8];
#pragma unroll
            for (int nt = 0; nt < 4; ++nt) {
                bf8v bbv = *(const bf8v*)&VT[(16 * nt + l15) * 72 + ks * 32 + q * 8];
                accY[nt] = __builtin_amdgcn_mfma_f32_16x16x32_bf16(a, bbv, accY[nt], 0, 0, 0);
            }
        }
#pragma unroll
        for (int ks = 0; ks < 2; ++ks) {
            bf8v a = *(const bf8v*)&rp[(16 * wv + l15) * 72 + ks * 32 + q * 8];
#pragma unroll
            for (int nt = 0; nt < 4; ++nt) {
                bf8v bbv = *(const bf8v*)&ScT[(16 * nt + l15) * 72 + ks * 32 + q * 8];
                accY[nt] = __builtin_amdgcn_mfma_f32_16x16x32_bf16(a, bbv, accY[nt], 0, 0, 0);
            }
        }

        float sum_[4] = {0.f, 0.f, 0.f, 0.f}, sq_[4] = {0.f, 0.f, 0.f, 0.f};
#pragma unroll
        for (int nt = 0; nt < 4; ++nt)
#pragma unroll
            for (int jr = 0; jr < 4; ++jr) {
                float yv = accY[nt][jr] * 0.125f;
                accY[nt][jr] = yv;
                sum_[jr] += yv;
                sq_[jr] += yv * yv;
            }
#pragma unroll
        for (int m = 1; m < 16; m <<= 1)
#pragma unroll
            for (int jr = 0; jr < 4; ++jr) {
                sum_[jr] += __shfl_xor(sum_[jr], m);
                sq_[jr] += __shfl_xor(sq_[jr], m);
            }
        float mu_[4], rstd_[4];
#pragma unroll
        for (int jr = 0; jr < 4; ++jr) {
            mu_[jr] = sum_[jr] * (1.f / Nq);
            rstd_[jr] = rsqrtf(sq_[jr] * (1.f / Nq) - mu_[jr] * mu_[jr] + EPSq);
        }
#pragma unroll
        for (int nt = 0; nt < 4; ++nt)
#pragma unroll
            for (int jr = 0; jr < 4; ++jr) {
                const int t = 16 * wv + q * 4 + jr;
                const float gate = bf2f(Gsh[t * 72 + 16 * nt + l15]);
                const float val = (accY[nt][jr] - mu_[jr]) * rstd_[jr] * lwj[nt] + lbj[nt];
                ao[(rowbase + c * 64 + t) * Cq + colbase + 16 * nt + l15] = f2bf(val * gate);
            }

        f32x4 accU[4];
#pragma unroll
        for (int nt = 0; nt < 4; ++nt) accU[nt] = {0.f, 0.f, 0.f, 0.f};
#pragma unroll
        for (int ks = 0; ks < 2; ++ks) {
            bf8v a = *(const bf8v*)&kdT[(16 * wv + l15) * 72 + ks * 32 + q * 8];
#pragma unroll
            for (int nt = 0; nt < 4; ++nt) {
                bf8v bbv = *(const bf8v*)&VT[(16 * nt + l15) * 72 + ks * 32 + q * 8];
                accU[nt] = __builtin_amdgcn_mfma_f32_16x16x32_bf16(a, bbv, accU[nt], 0, 0, 0);
            }
        }
        __syncthreads();
#pragma unroll
        for (int nt = 0; nt < 4; ++nt) {
#pragma unroll
            for (int jr = 0; jr < 4; ++jr)
                S[nt][jr] = ewL[jr] * S[nt][jr] + accU[nt][jr];
            ushort4 sc;
            sc.x = f2bf(S[nt][0]); sc.y = f2bf(S[nt][1]);
            sc.z = f2bf(S[nt][2]); sc.w = f2bf(S[nt][3]);
            *(ushort4*)&ScT[(16 * nt + l15) * 72 + 16 * wv + q * 4] = sc;
        }
        __syncthreads();
    }
}

// ---------------- launcher ----------------
extern "C" void kernel_launch(void* const* d_in, const int* in_sizes, int n_in,
                              void* d_out, int out_size, void* d_ws, size_t ws_size,
                              hipStream_t stream) {
    const float* x     = (const float*)d_in[0];
    const float* ln0w  = (const float*)d_in[1];
    const float* ln0b  = (const float*)d_in[2];
    const float* ln1w  = (const float*)d_in[3];
    const float* ln1b  = (const float*)d_in[4];
    const float* ln2w  = (const float*)d_in[5];
    const float* ln2b  = (const float*)d_in[6];
    const float* atmk  = (const float*)d_in[7];
    const float* atmv  = (const float*)d_in[8];
    const float* atmr  = (const float*)d_in[9];
    const float* atmg  = (const float*)d_in[10];
    const float* decay = (const float*)d_in[11];
    const float* faaaa = (const float*)d_in[12];
    const float* aWr   = (const float*)d_in[13];
    const float* aWk   = (const float*)d_in[14];
    const float* aWv   = (const float*)d_in[15];
    const float* aWg   = (const float*)d_in[16];
    const float* aWo   = (const float*)d_in[17];
    const float* lnxw  = (const float*)d_in[18];
    const float* lnxb  = (const float*)d_in[19];
    const float* ftmk  = (const float*)d_in[20];
    const float* ftmr  = (const float*)d_in[21];
    const float* fWk   = (const float*)d_in[22];
    const float* fWr   = (const float*)d_in[23];
    const float* fWv   = (const float*)d_in[24];

    const size_t MB = 1024ull * 1024ull;
    const size_t WS_NEEDED = 250 * MB;
    dim3 blk(256);

    if (ws_size < WS_NEEDED) {
        diag_kernel<<<out_size / 1024, blk, 0, stream>>>((float*)d_out,
            1000.f + (float)((double)ws_size / (double)MB));
        return;
    }

    char* ws = (char*)d_ws;
    unsigned short* WR  = (unsigned short*)(ws + 0 * MB);
    unsigned short* WK  = (unsigned short*)(ws + 2 * MB);
    unsigned short* WV  = (unsigned short*)(ws + 4 * MB);
    unsigned short* WG  = (unsigned short*)(ws + 6 * MB);
    unsigned short* WO  = (unsigned short*)(ws + 8 * MB);
    unsigned short* FWK = (unsigned short*)(ws + 10 * MB);
    unsigned short* FWR = (unsigned short*)(ws + 17 * MB);
    unsigned short* FWV = (unsigned short*)(ws + 19 * MB);
    unsigned short* XN  = (unsigned short*)(ws + 26 * MB);
    unsigned short* MXR = (unsigned short*)(ws + 58 * MB);
    unsigned short* MXK = (unsigned short*)(ws + 90 * MB);
    unsigned short* MXV = (unsigned short*)(ws + 122 * MB);
    unsigned short* MXG = (unsigned short*)(ws + 154 * MB);
    unsigned short* Rb  = (unsigned short*)(ws + 186 * MB);
    unsigned short* Kb  = (unsigned short*)(ws + 58 * MB);
    unsigned short* Vb  = (unsigned short*)(ws + 90 * MB);
    unsigned short* Gb  = (unsigned short*)(ws + 122 * MB);
    unsigned short* AO  = (unsigned short*)(ws + 154 * MB);
    unsigned short* XK2 = (unsigned short*)(ws + 58 * MB);
    unsigned short* XR2 = (unsigned short*)(ws + 90 * MB);
    unsigned short* KF  = (unsigned short*)(ws + 122 * MB);
    unsigned short* SRb = (unsigned short*)(ws + 26 * MB);
    float*          X0  = (float*)d_out;

    const int NTOK = Bq * Tq;  // 16384
    dim3 blk512(512);
    const int gsq = (NTOK / 256) * (Cq / 128);    // 64*8  = 512 blocks (2/CU)
    const int gup = (NTOK / 256) * (FFNq / 128);  // 64*28 = 1792 blocks

    f2bf_all_kernel<<<13312, blk, 0, stream>>>(aWr, aWk, aWv, aWg, aWo, fWk, fWr, fWv,
                                               WR, WK, WV, WG, WO, FWK, FWR, FWV);

    ln01_kernel<<<NTOK, blk, 0, stream>>>(x, ln0w, ln0b, ln1w, ln1b, X0, XN);

    mix4_kernel<<<NTOK, blk, 0, stream>>>(XN, atmr, atmk, atmv, atmg,
                                          (ushort4*)MXR, (ushort4*)MXK,
                                          (ushort4*)MXV, (ushort4*)MXG);

    gemm128<6><<<gsq, blk512, 0, stream>>>(MXR, WR, Cq, Cq, nullptr, Rb, nullptr, nullptr);
    gemm128<6><<<gsq, blk512, 0, stream>>>(MXK, WK, Cq, Cq, nullptr, Kb, nullptr, nullptr);
    gemm128<6><<<gsq, blk512, 0, stream>>>(MXV, WV, Cq, Cq, nullptr, Vb, nullptr, nullptr);
    gemm128<1><<<gsq, blk512, 0, stream>>>(MXG, WG, Cq, Cq, nullptr, Gb, nullptr, nullptr);

    wkv_kernel<<<Bq * Hq, blk, 0, stream>>>(Rb, Kb, Vb, Gb, decay, faaaa, lnxw, lnxb, AO);
    gemm128<2><<<gsq, blk512, 0, stream>>>(AO, WO, Cq, Cq, X0, nullptr, X0, nullptr);

    ln_kernel<<<NTOK, blk, 0, stream>>>(X0, ln2w, ln2b, XN);
    mix2_kernel<<<NTOK, blk, 0, stream>>>(XN, ftmk, ftmr, (ushort4*)XK2, (ushort4*)XR2);
    gemm128<3><<<gup, blk512, 0, stream>>>(XK2, FWK, Cq, FFNq, nullptr, KF, nullptr, nullptr);
    gemm128<4><<<gsq, blk512, 0, stream>>>(XR2, FWR, Cq, Cq, nullptr, SRb, nullptr, nullptr);
    gemm128<5><<<gsq, blk512, 0, stream>>>(KF, FWV, FFNq, Cq, X0, nullptr, X0, SRb);
}

// Round 7
// 916.324 us; speedup vs baseline: 1.0914x; 1.0298x over previous
//
#include <hip/hip_runtime.h>

#define Bq 8
#define Tq 2048
#define Cq 1024
#define Hq 16
#define Nq 64
#define FFNq 3584
#define EPSq 1e-5f

typedef __bf16 bf8v __attribute__((ext_vector_type(8)));
typedef float f32x4 __attribute__((ext_vector_type(4)));

typedef __attribute__((address_space(1))) const unsigned int GU;
typedef __attribute__((address_space(3))) unsigned int LU;

__device__ __forceinline__ void gload16(const unsigned short* g, unsigned short* l) {
    __builtin_amdgcn_global_load_lds((GU*)g, (LU*)l, 16, 0, 0);
}

__device__ __forceinline__ unsigned short f2bf(float f) {
    unsigned u = __float_as_uint(f);
    u += 0x7fffu + ((u >> 16) & 1u);   // round-to-nearest-even
    return (unsigned short)(u >> 16);
}
__device__ __forceinline__ float bf2f(unsigned short h) {
    return __uint_as_float(((unsigned)h) << 16);
}

// ---------------- diagnostic fill (ws too small) ----------------
__global__ __launch_bounds__(256)
void diag_kernel(float* __restrict__ out, float val) {
    int i = (blockIdx.x * 256 + threadIdx.x) * 4;
    float4 v = make_float4(val, val, val, val);
    *(float4*)(out + i) = v;
}

// ---------------- fp32 -> bf16 conversion, all 8 weights in one launch -------
__global__ __launch_bounds__(256)
void f2bf_all_kernel(const float* __restrict__ s0, const float* __restrict__ s1,
                     const float* __restrict__ s2, const float* __restrict__ s3,
                     const float* __restrict__ s4, const float* __restrict__ s5,
                     const float* __restrict__ s6, const float* __restrict__ s7,
                     unsigned short* __restrict__ d0, unsigned short* __restrict__ d1,
                     unsigned short* __restrict__ d2, unsigned short* __restrict__ d3,
                     unsigned short* __restrict__ d4, unsigned short* __restrict__ d5,
                     unsigned short* __restrict__ d6, unsigned short* __restrict__ d7) {
    int b = blockIdx.x;
    const float* src; unsigned short* dst;
    if      (b < 1024)  { src = s0; dst = d0; }
    else if (b < 2048)  { src = s1; dst = d1; b -= 1024; }
    else if (b < 3072)  { src = s2; dst = d2; b -= 2048; }
    else if (b < 4096)  { src = s3; dst = d3; b -= 3072; }
    else if (b < 5120)  { src = s4; dst = d4; b -= 4096; }
    else if (b < 8704)  { src = s5; dst = d5; b -= 5120; }
    else if (b < 9728)  { src = s6; dst = d6; b -= 8704; }
    else                { src = s7; dst = d7; b -= 9728; }
    int i = (b * 256 + threadIdx.x) * 4;
    float4 v = *(const float4*)(src + i);
    ushort4 o;
    o.x = f2bf(v.x); o.y = f2bf(v.y); o.z = f2bf(v.z); o.w = f2bf(v.w);
    *(ushort4*)(dst + i) = o;
}

// ---------------- block reduction helper (256 threads) ----------------
__device__ __forceinline__ void blockred2(float& a, float& b, float* sm) {
#pragma unroll
    for (int m = 1; m < 64; m <<= 1) { a += __shfl_xor(a, m); b += __shfl_xor(b, m); }
    const int w = threadIdx.x >> 6;
    __syncthreads();
    if ((threadIdx.x & 63) == 0) { sm[w] = a; sm[4 + w] = b; }
    __syncthreads();
    a = sm[0] + sm[1] + sm[2] + sm[3];
    b = sm[4] + sm[5] + sm[6] + sm[7];
}

// ---------------- ln0 + ln1 fused: x -> x0 (fp32), xn (bf16) ----------------
__global__ __launch_bounds__(256)
void ln01_kernel(const float* __restrict__ x,
                 const float* __restrict__ w0, const float* __restrict__ b0,
                 const float* __restrict__ w1, const float* __restrict__ b1,
                 float* __restrict__ x0, unsigned short* __restrict__ xn) {
    __shared__ float sm[8];
    const int tok = blockIdx.x, tid = threadIdx.x, c = tid * 4;
    const size_t base = (size_t)tok * Cq + c;
    float4 v = *(const float4*)(x + base);
    float s = v.x + v.y + v.z + v.w;
    float ss = v.x * v.x + v.y * v.y + v.z * v.z + v.w * v.w;
    blockred2(s, ss, sm);
    float mu = s * (1.f / Cq);
    float rstd = rsqrtf(ss * (1.f / Cq) - mu * mu + EPSq);
    float4 wv = *(const float4*)(w0 + c), bv = *(const float4*)(b0 + c);
    float4 e;
    e.x = (v.x - mu) * rstd * wv.x + bv.x;
    e.y = (v.y - mu) * rstd * wv.y + bv.y;
    e.z = (v.z - mu) * rstd * wv.z + bv.z;
    e.w = (v.w - mu) * rstd * wv.w + bv.w;
    *(float4*)(x0 + base) = e;
    s = e.x + e.y + e.z + e.w;
    ss = e.x * e.x + e.y * e.y + e.z * e.z + e.w * e.w;
    blockred2(s, ss, sm);
    mu = s * (1.f / Cq);
    rstd = rsqrtf(ss * (1.f / Cq) - mu * mu + EPSq);
    wv = *(const float4*)(w1 + c); bv = *(const float4*)(b1 + c);
    ushort4 o;
    o.x = f2bf((e.x - mu) * rstd * wv.x + bv.x);
    o.y = f2bf((e.y - mu) * rstd * wv.y + bv.y);
    o.z = f2bf((e.z - mu) * rstd * wv.z + bv.z);
    o.w = f2bf((e.w - mu) * rstd * wv.w + bv.w);
    *(ushort4*)(xn + base) = o;
}

// ---------------- single layernorm (ln2): fp32 in -> bf16 out ----------------
__global__ __launch_bounds__(256)
void ln_kernel(const float* __restrict__ x, const float* __restrict__ w,
               const float* __restrict__ b, unsigned short* __restrict__ out) {
    __shared__ float sm[8];
    const int tok = blockIdx.x, tid = threadIdx.x, c = tid * 4;
    const size_t base = (size_t)tok * Cq + c;
    float4 v = *(const float4*)(x + base);
    float s = v.x + v.y + v.z + v.w;
    float ss = v.x * v.x + v.y * v.y + v.z * v.z + v.w * v.w;
    blockred2(s, ss, sm);
    float mu = s * (1.f / Cq);
    float rstd = rsqrtf(ss * (1.f / Cq) - mu * mu + EPSq);
    float4 wv = *(const float4*)(w + c), bv = *(const float4*)(b + c);
    ushort4 o;
    o.x = f2bf((v.x - mu) * rstd * wv.x + bv.x);
    o.y = f2bf((v.y - mu) * rstd * wv.y + bv.y);
    o.z = f2bf((v.z - mu) * rstd * wv.z + bv.z);
    o.w = f2bf((v.w - mu) * rstd * wv.w + bv.w);
    *(ushort4*)(out + base) = o;
}

// ---------------- token-shift: 4 mixes in one pass (time-mix) ----------------
__device__ __forceinline__ ushort4 mixpack(float ax, float ay, float az, float aw,
                                           float px, float py, float pz, float pw,
                                           const float4& m) {
    ushort4 o;
    o.x = f2bf(px + m.x * (ax - px));
    o.y = f2bf(py + m.y * (ay - py));
    o.z = f2bf(pz + m.z * (az - pz));
    o.w = f2bf(pw + m.w * (aw - pw));
    return o;
}

__global__ __launch_bounds__(256)
void mix4_kernel(const unsigned short* __restrict__ xn,
                 const float* __restrict__ tmr, const float* __restrict__ tmk,
                 const float* __restrict__ tmv, const float* __restrict__ tmg,
                 ushort4* __restrict__ outR, ushort4* __restrict__ outK,
                 ushort4* __restrict__ outV, ushort4* __restrict__ outG) {
    const int tok = blockIdx.x, tid = threadIdx.x, c = tid * 4;
    const int t = tok & (Tq - 1);
    const size_t base = (size_t)tok * Cq + c;
    ushort4 a = *(const ushort4*)(xn + base);
    ushort4 p = make_ushort4(0, 0, 0, 0);
    if (t) p = *(const ushort4*)(xn + base - Cq);
    float ax = bf2f(a.x), ay = bf2f(a.y), az = bf2f(a.z), aw = bf2f(a.w);
    float px = bf2f(p.x), py = bf2f(p.y), pz = bf2f(p.z), pw = bf2f(p.w);
    const size_t b4 = (size_t)tok * 256 + tid;
    outR[b4] = mixpack(ax, ay, az, aw, px, py, pz, pw, *(const float4*)(tmr + c));
    outK[b4] = mixpack(ax, ay, az, aw, px, py, pz, pw, *(const float4*)(tmk + c));
    outV[b4] = mixpack(ax, ay, az, aw, px, py, pz, pw, *(const float4*)(tmv + c));
    outG[b4] = mixpack(ax, ay, az, aw, px, py, pz, pw, *(const float4*)(tmg + c));
}

// ---------------- token-shift: 2 mixes in one pass (channel-mix) -------------
__global__ __launch_bounds__(256)
void mix2_kernel(const unsigned short* __restrict__ xn,
                 const float* __restrict__ tmk, const float* __restrict__ tmr,
                 ushort4* __restrict__ outK, ushort4* __restrict__ outR) {
    const int tok = blockIdx.x, tid = threadIdx.x, c = tid * 4;
    const int t = tok & (Tq - 1);
    const size_t base = (size_t)tok * Cq + c;
    ushort4 a = *(const ushort4*)(xn + base);
    ushort4 p = make_ushort4(0, 0, 0, 0);
    if (t) p = *(const ushort4*)(xn + base - Cq);
    float ax = bf2f(a.x), ay = bf2f(a.y), az = bf2f(a.z), aw = bf2f(a.w);
    float px = bf2f(p.x), py = bf2f(p.y), pz = bf2f(p.z), pw = bf2f(p.w);
    const size_t b4 = (size_t)tok * 256 + tid;
    outK[b4] = mixpack(ax, ay, az, aw, px, py, pz, pw, *(const float4*)(tmk + c));
    outR[b4] = mixpack(ax, ay, az, aw, px, py, pz, pw, *(const float4*)(tmr + c));
}

// ---------------- 256x128 TLP-first bf16 MFMA GEMM body ----------------------
// (R6 structure, best measured: 157 us MODE5, occ 35%, VGPR 64.)
// 512 threads = 8 waves (4M x 2N), per-wave 64x64 (acc[4][4]).  BK=32; LDS
// ring of 3 slots x 24KB = 72 KiB -> 2 blocks/CU.  Per K-step: issue 3
// gload_lds for slot (k+2)%3; 8x ds_read_b128; 16 MFMA; vmcnt(3) (certifies
// k+1; never 0 until tail); barrier.  Swizzle: LDS(row,u) holds global chunk
// u^(row&3); frag reads chunk q^(l15&3); staging source pre-swizzled.
// mode: 1 silu->bf16; 2 res+acc->fp32; 3 relu^2->bf16; 4 sigmoid->bf16;
//       5 res+bf2f(sg)*acc->fp32; 6 plain->bf16.
__device__ __forceinline__ void gemm_body(
    const unsigned short* __restrict__ A, const unsigned short* __restrict__ W,
    int K, int N, int mode,
    float* __restrict__ outF, unsigned short* __restrict__ outB,
    const float* __restrict__ res, const unsigned short* __restrict__ sg,
    int m0, int n0, unsigned short* lds) {
    const int tid = threadIdx.x;
    const int wid = tid >> 6, lane = tid & 63;
    const int wr = wid >> 1, wc = wid & 1;       // wave grid 4 (M) x 2 (N)
    const int l15 = lane & 15, q = lane >> 4;

    const int srow = tid >> 2;
    const int scol = ((tid & 3) ^ ((tid >> 2) & 3)) * 8;
    const unsigned short* aS0 = A + (size_t)(m0 + srow) * K + scol;
    const unsigned short* aS1 = A + (size_t)(m0 + 128 + srow) * K + scol;
    const unsigned short* wS  = W + (size_t)(n0 + srow) * K + scol;

    const int fco = (q ^ (l15 & 3)) * 8;
    const int aOff = (wr * 64 + l15) * 32 + fco;          // + mi*512
    const int bOff = 8192 + (wc * 64 + l15) * 32 + fco;   // + ni*512

    f32x4 acc[4][4];
#pragma unroll
    for (int mi = 0; mi < 4; ++mi)
#pragma unroll
        for (int ni = 0; ni < 4; ++ni)
            acc[mi][ni] = {0.f, 0.f, 0.f, 0.f};

    const int NJ = K >> 5;

#pragma unroll
    for (int j = 0; j < 2; ++j) {
        gload16(aS0 + j * 32, lds + j * 12288 + tid * 8);
        gload16(aS1 + j * 32, lds + j * 12288 + 4096 + tid * 8);
        gload16(wS  + j * 32, lds + j * 12288 + 8192 + tid * 8);
    }
    asm volatile("s_waitcnt vmcnt(3)" ::: "memory");
    __builtin_amdgcn_s_barrier();

    unsigned short* L0 = lds;
    unsigned short* L1 = lds + 12288;
    unsigned short* L2 = lds + 24576;

    for (int k = 0; k < NJ; ++k) {
        if (k + 2 < NJ) {
            gload16(aS0 + (k + 2) * 32, L2 + tid * 8);
            gload16(aS1 + (k + 2) * 32, L2 + 4096 + tid * 8);
            gload16(wS  + (k + 2) * 32, L2 + 8192 + tid * 8);
        }
        bf8v a[4], b[4];
#pragma unroll
        for (int i = 0; i < 4; ++i) a[i] = *(const bf8v*)&L0[aOff + i * 512];
#pragma unroll
        for (int i = 0; i < 4; ++i) b[i] = *(const bf8v*)&L0[bOff + i * 512];
        __builtin_amdgcn_s_setprio(1);
#pragma unroll
        for (int mi = 0; mi < 4; ++mi)
#pragma unroll
            for (int ni = 0; ni < 4; ++ni)
                acc[mi][ni] = __builtin_amdgcn_mfma_f32_16x16x32_bf16(a[mi], b[ni], acc[mi][ni], 0, 0, 0);
        __builtin_amdgcn_s_setprio(0);
        if (k < NJ - 2) {
            asm volatile("s_waitcnt vmcnt(3)" ::: "memory");
            __builtin_amdgcn_s_barrier();
        } else if (k == NJ - 2) {
            asm volatile("s_waitcnt vmcnt(0)" ::: "memory");
            __builtin_amdgcn_s_barrier();
        }
        unsigned short* t0 = L0; L0 = L1; L1 = L2; L2 = t0;
    }

#pragma unroll
    for (int mi = 0; mi < 4; ++mi)
#pragma unroll
        for (int ni = 0; ni < 4; ++ni)
#pragma unroll
            for (int j = 0; j < 4; ++j) {
                const int row = m0 + wr * 64 + mi * 16 + q * 4 + j;
                const int col = n0 + wc * 64 + ni * 16 + l15;
                const size_t idx = (size_t)row * N + col;
                const float av = acc[mi][ni][j];
                if (mode == 1) {
                    outB[idx] = f2bf(av / (1.f + __expf(-av)));
                } else if (mode == 2) {
                    outF[idx] = res[idx] + av;
                } else if (mode == 3) {
                    float tt = fmaxf(av, 0.f);
                    outB[idx] = f2bf(tt * tt);
                } else if (mode == 4) {
                    outB[idx] = f2bf(1.f / (1.f + __expf(-av)));
                } else if (mode == 5) {
                    outF[idx] = res[idx] + bf2f(sg[idx]) * av;
                } else {
                    outB[idx] = f2bf(av);
                }
            }
}

// standalone gemm (XCD-swizzled), for Wo (MODE 2), down-proj (MODE 5), G (MODE 1)
template<int MODE>
__global__ __launch_bounds__(512, 4)
void gemm128(const unsigned short* __restrict__ A, const unsigned short* __restrict__ W,
             int K, int N, float* __restrict__ outF, unsigned short* __restrict__ outB,
             const float* __restrict__ res, const unsigned short* __restrict__ sg) {
    __shared__ unsigned short lds[3][12288];
    const int nn = N >> 7;
    const int q8 = gridDim.x >> 3;
    const int bid = blockIdx.x;
    const int swz = (bid & 7) * q8 + (bid >> 3);
    const int m0 = (swz / nn) * 256;
    const int n0 = (swz % nn) * 128;
    gemm_body(A, W, K, N, MODE, outF, outB, res, sg, m0, n0, &lds[0][0]);
}

// fused R/K/V projections: 3 segments x 512 blocks, all MODE 6 (plain).
// Outputs chosen to never alias any of the three concurrently-read inputs.
__global__ __launch_bounds__(512, 4)
void proj3_kernel(const unsigned short* __restrict__ A0, const unsigned short* __restrict__ A1,
                  const unsigned short* __restrict__ A2,
                  const unsigned short* __restrict__ W0, const unsigned short* __restrict__ W1,
                  const unsigned short* __restrict__ W2,
                  unsigned short* __restrict__ O0, unsigned short* __restrict__ O1,
                  unsigned short* __restrict__ O2) {
    __shared__ unsigned short lds[3][12288];
    const int bid = blockIdx.x;
    const int seg = bid >> 9, inner = bid & 511;
    const unsigned short* A; const unsigned short* W; unsigned short* O;
    if (seg == 0)      { A = A0; W = W0; O = O0; }
    else if (seg == 1) { A = A1; W = W1; O = O1; }
    else               { A = A2; W = W2; O = O2; }
    const int swz = (inner & 7) * 64 + (inner >> 3);   // 512 blocks: q8=64
    const int m0 = (swz >> 3) * 256;                   // nn=8
    const int n0 = (swz & 7) * 128;
    gemm_body(A, W, Cq, Cq, 6, nullptr, O, nullptr, nullptr, m0, n0, &lds[0][0]);
}

// fused FFN up (relu^2, N=3584, 1792 blocks) + FFN sigmoid (N=1024, 512 blocks)
__global__ __launch_bounds__(512, 4)
void ffn2_kernel(const unsigned short* __restrict__ XK2, const unsigned short* __restrict__ FWK,
                 unsigned short* __restrict__ KF,
                 const unsigned short* __restrict__ XR2, const unsigned short* __restrict__ FWR,
                 unsigned short* __restrict__ SRb) {
    __shared__ unsigned short lds[3][12288];
    const int bid = blockIdx.x;
    if (bid < 1792) {
        const int swz = (bid & 7) * 224 + (bid >> 3);  // q8 = 1792/8 = 224
        const int m0 = (swz / 28) * 256;               // nn = 28
        const int n0 = (swz % 28) * 128;
        gemm_body(XK2, FWK, Cq, FFNq, 3, nullptr, KF, nullptr, nullptr, m0, n0, &lds[0][0]);
    } else {
        const int inner = bid - 1792;
        const int swz = (inner & 7) * 64 + (inner >> 3);
        const int m0 = (swz >> 3) * 256;
        const int n0 = (swz & 7) * 128;
        gemm_body(XR2, FWR, Cq, Cq, 4, nullptr, SRb, nullptr, nullptr, m0, n0, &lds[0][0]);
    }
}

// ---------------- WKV5: chunked linear attention + fused GroupNorm*gate ------
// Decay-power tables (rpw/kmw/kdw) hoisted out of the 32-chunk loop: they
// depend only on (thread row, channel) -> computed once into 48 registers,
// saving 48 exp2f x 31 chunks per thread (bitwise-identical numerics).
__global__ __launch_bounds__(256)
void wkv_kernel(const unsigned short* __restrict__ r, const unsigned short* __restrict__ k,
                const unsigned short* __restrict__ v, const unsigned short* __restrict__ g,
                const float* __restrict__ decay, const float* __restrict__ faaaa,
                const float* __restrict__ lnxw, const float* __restrict__ lnxb,
                unsigned short* __restrict__ ao) {
    __shared__ unsigned short rp[64 * 72], km[64 * 72], kdT[64 * 72];
    __shared__ unsigned short VT[64 * 72], Abf[64 * 72], ScT[64 * 72], Gsh[64 * 72];
    __shared__ float Dt[64];
    const int tid = threadIdx.x;
    const int bh = blockIdx.x, b = bh >> 4, h = bh & 15;
    const int tr = tid >> 2, g4 = tid & 3, i0 = g4 * 16;
    const int wv = tid >> 6, lane = tid & 63, l15 = lane & 15, q = lane >> 4;
    const float LOG2E = 1.44269504088896340736f;
    const float ftr = (float)tr;

    float l2w[16], uu[16];
#pragma unroll
    for (int ii = 0; ii < 16; ++ii) {
        l2w[ii] = -__expf(decay[h * Nq + i0 + ii]) * LOG2E;
        uu[ii] = faaaa[h * Nq + i0 + ii];
    }
    float rpw[16], kmw[16], kdw[16];
#pragma unroll
    for (int ii = 0; ii < 16; ++ii) {
        rpw[ii] = exp2f(ftr * l2w[ii]);
        kmw[ii] = exp2f(-(ftr + 1.f) * l2w[ii]);
        kdw[ii] = exp2f((63.f - ftr) * l2w[ii]);
    }
    float ewL[4];
#pragma unroll
    for (int jr = 0; jr < 4; ++jr) {
        float lw = -__expf(decay[h * Nq + 16 * wv + q * 4 + jr]) * LOG2E;
        ewL[jr] = exp2f(64.f * lw);
    }
    const int colbase = h * Nq;
    float lwj[4], lbj[4];
#pragma unroll
    for (int nt = 0; nt < 4; ++nt) {
        lwj[nt] = lnxw[colbase + 16 * nt + l15];
        lbj[nt] = lnxb[colbase + 16 * nt + l15];
    }
    f32x4 S[4];
#pragma unroll
    for (int nt = 0; nt < 4; ++nt) S[nt] = {0.f, 0.f, 0.f, 0.f};
    for (int idx = tid; idx < 64 * 72; idx += 256) ScT[idx] = 0;
    __syncthreads();

    const size_t rowbase = (size_t)b * Tq;

    for (int c = 0; c < 32; ++c) {
        const size_t grow = (rowbase + c * 64 + tr) * Cq + colbase + i0;
        unsigned short rs_[16], ks_[16], vs_[16];
        *(uint4*)&rs_[0] = *(const uint4*)(r + grow);
        *(uint4*)&rs_[8] = *(const uint4*)(r + grow + 8);
        *(uint4*)&ks_[0] = *(const uint4*)(k + grow);
        *(uint4*)&ks_[8] = *(const uint4*)(k + grow + 8);
        *(uint4*)&vs_[0] = *(const uint4*)(v + grow);
        *(uint4*)&vs_[8] = *(const uint4*)(v + grow + 8);
        *(uint4*)&Gsh[tr * 72 + i0] = *(const uint4*)(g + grow);
        *(uint4*)&Gsh[tr * 72 + i0 + 8] = *(const uint4*)(g + grow + 8);
        float pd = 0.f;
#pragma unroll
        for (int ii = 0; ii < 16; ++ii) {
            float rf = bf2f(rs_[ii]), kf = bf2f(ks_[ii]);
            rp[tr * 72 + i0 + ii] = f2bf(rf * rpw[ii]);
            km[tr * 72 + i0 + ii] = f2bf(kf * kmw[ii]);
            kdT[(i0 + ii) * 72 + tr] = f2bf(kf * kdw[ii]);
            VT[(i0 + ii) * 72 + tr] = vs_[ii];
            pd += rf * uu[ii] * kf;
        }
        pd += __shfl_xor(pd, 1);
        pd += __shfl_xor(pd, 2);
        if (g4 == 0) Dt[tr] = pd;
        __syncthreads();

        f32x4 accA[4];
#pragma unroll
        for (int nt = 0; nt < 4; ++nt) accA[nt] = {0.f, 0.f, 0.f, 0.f};
#pragma unroll
        for (int ks = 0; ks < 2; ++ks) {
            bf8v a = *(const bf8v*)&rp[(16 * wv + l15) * 72 + ks * 32 + q * 8];
#pragma unroll
            for (int nt = 0; nt < 4; ++nt) {
                bf8v bbv = *(const bf8v*)&km[(16 * nt + l15) * 72 + ks * 32 + q * 8];
                accA[nt] = __builtin_amdgcn_mfma_f32_16x16x32_bf16(a, bbv, accA[nt], 0, 0, 0);
            }
        }
#pragma unroll
        for (int nt = 0; nt < 4; ++nt)
#pragma unroll
            for (int jr = 0; jr < 4; ++jr) {
                const int t = 16 * wv + q * 4 + jr, s = 16 * nt + l15;
                const float a = accA[nt][jr];
                const float val = (s < t) ? a : ((s == t) ? Dt[t] : 0.f);
                Abf[t * 72 + s] = f2bf(val);
            }

        f32x4 accY[4];
#pragma unroll
        for (int nt = 0; nt < 4; ++nt) accY[nt] = {0.f, 0.f, 0.f, 0.f};
#pragma unroll
        for (int ks = 0; ks < 2; ++ks) {
            bf8v a = *(const bf8v*)&Abf[(16 * wv + l15) * 72 + ks * 32 + q * 8];
#pragma unroll
            for (int nt = 0; nt < 4; ++nt) {
                bf8v bbv = *(const bf8v*)&VT[(16 * nt + l15) * 72 + ks * 32 + q * 8];
                accY[nt] = __builtin_amdgcn_mfma_f32_16x16x32_bf16(a, bbv, accY[nt], 0, 0, 0);
            }
        }
#pragma unroll
        for (int ks = 0; ks < 2; ++ks) {
            bf8v a = *(const bf8v*)&rp[(16 * wv + l15) * 72 + ks * 32 + q * 8];
#pragma unroll
            for (int nt = 0; nt < 4; ++nt) {
                bf8v bbv = *(const bf8v*)&ScT[(16 * nt + l15) * 72 + ks * 32 + q * 8];
                accY[nt] = __builtin_amdgcn_mfma_f32_16x16x32_bf16(a, bbv, accY[nt], 0, 0, 0);
            }
        }

        float sum_[4] = {0.f, 0.f, 0.f, 0.f}, sq_[4] = {0.f, 0.f, 0.f, 0.f};
#pragma unroll
        for (int nt = 0; nt < 4; ++nt)
#pragma unroll
            for (int jr = 0; jr < 4; ++jr) {
                float yv = accY[nt][jr] * 0.125f;
                accY[nt][jr] = yv;
                sum_[jr] += yv;
                sq_[jr] += yv * yv;
            }
#pragma unroll
        for (int m = 1; m < 16; m <<= 1)
#pragma unroll
            for (int jr = 0; jr < 4; ++jr) {
                sum_[jr] += __shfl_xor(sum_[jr], m);
                sq_[jr] += __shfl_xor(sq_[jr], m);
            }
        float mu_[4], rstd_[4];
#pragma unroll
        for (int jr = 0; jr < 4; ++jr) {
            mu_[jr] = sum_[jr] * (1.f / Nq);
            rstd_[jr] = rsqrtf(sq_[jr] * (1.f / Nq) - mu_[jr] * mu_[jr] + EPSq);
        }
#pragma unroll
        for (int nt = 0; nt < 4; ++nt)
#pragma unroll
            for (int jr = 0; jr < 4; ++jr) {
                const int t = 16 * wv + q * 4 + jr;
                const float gate = bf2f(Gsh[t * 72 + 16 * nt + l15]);
                const float val = (accY[nt][jr] - mu_[jr]) * rstd_[jr] * lwj[nt] + lbj[nt];
                ao[(rowbase + c * 64 + t) * Cq + colbase + 16 * nt + l15] = f2bf(val * gate);
            }

        f32x4 accU[4];
#pragma unroll
        for (int nt = 0; nt < 4; ++nt) accU[nt] = {0.f, 0.f, 0.f, 0.f};
#pragma unroll
        for (int ks = 0; ks < 2; ++ks) {
            bf8v a = *(const bf8v*)&kdT[(16 * wv + l15) * 72 + ks * 32 + q * 8];
#pragma unroll
            for (int nt = 0; nt < 4; ++nt) {
                bf8v bbv = *(const bf8v*)&VT[(16 * nt + l15) * 72 + ks * 32 + q * 8];
                accU[nt] = __builtin_amdgcn_mfma_f32_16x16x32_bf16(a, bbv, accU[nt], 0, 0, 0);
            }
        }
        __syncthreads();
#pragma unroll
        for (int nt = 0; nt < 4; ++nt) {
#pragma unroll
            for (int jr = 0; jr < 4; ++jr)
                S[nt][jr] = ewL[jr] * S[nt][jr] + accU[nt][jr];
            ushort4 sc;
            sc.x = f2bf(S[nt][0]); sc.y = f2bf(S[nt][1]);
            sc.z = f2bf(S[nt][2]); sc.w = f2bf(S[nt][3]);
            *(ushort4*)&ScT[(16 * nt + l15) * 72 + 16 * wv + q * 4] = sc;
        }
        __syncthreads();
    }
}

// ---------------- launcher ----------------
// Workspace plan (liveness-verified for concurrent fused segments):
//   0-26   weights (bf16)
//   26-58  XN (ln01 out; dead after mix4) -> Vb (proj3 out) -> after wkv dead
//          -> XN2 (ln out) -> SRb region? no: SRb = 26 (ln's XN consumed by mix2)
//   58-90  MXR (dead after proj3) -> Gb (G-gemm out; dead after wkv) -> XK2
//   90-122 MXK (dead after proj3) -> XR2
//   122-154 MXV (dead after proj3) -> KF (122..234, overlaps dead AO/Rb/Kb)
//   154-186 MXG (dead after G-gemm) -> AO (dead after Wo-gemm)
//   186-218 Rb (dead after wkv)
//   218-250 Kb (dead after wkv)
extern "C" void kernel_launch(void* const* d_in, const int* in_sizes, int n_in,
                              void* d_out, int out_size, void* d_ws, size_t ws_size,
                              hipStream_t stream) {
    const float* x     = (const float*)d_in[0];
    const float* ln0w  = (const float*)d_in[1];
    const float* ln0b  = (const float*)d_in[2];
    const float* ln1w  = (const float*)d_in[3];
    const float* ln1b  = (const float*)d_in[4];
    const float* ln2w  = (const float*)d_in[5];
    const float* ln2b  = (const float*)d_in[6];
    const float* atmk  = (const float*)d_in[7];
    const float* atmv  = (const float*)d_in[8];
    const float* atmr  = (const float*)d_in[9];
    const float* atmg  = (const float*)d_in[10];
    const float* decay = (const float*)d_in[11];
    const float* faaaa = (const float*)d_in[12];
    const float* aWr   = (const float*)d_in[13];
    const float* aWk   = (const float*)d_in[14];
    const float* aWv   = (const float*)d_in[15];
    const float* aWg   = (const float*)d_in[16];
    const float* aWo   = (const float*)d_in[17];
    const float* lnxw  = (const float*)d_in[18];
    const float* lnxb  = (const float*)d_in[19];
    const float* ftmk  = (const float*)d_in[20];
    const float* ftmr  = (const float*)d_in[21];
    const float* fWk   = (const float*)d_in[22];
    const float* fWr   = (const float*)d_in[23];
    const float* fWv   = (const float*)d_in[24];

    const size_t MB = 1024ull * 1024ull;
    const size_t WS_NEEDED = 250 * MB;
    dim3 blk(256);

    if (ws_size < WS_NEEDED) {
        diag_kernel<<<out_size / 1024, blk, 0, stream>>>((float*)d_out,
            1000.f + (float)((double)ws_size / (double)MB));
        return;
    }

    char* ws = (char*)d_ws;
    unsigned short* WR  = (unsigned short*)(ws + 0 * MB);
    unsigned short* WK  = (unsigned short*)(ws + 2 * MB);
    unsigned short* WV  = (unsigned short*)(ws + 4 * MB);
    unsigned short* WG  = (unsigned short*)(ws + 6 * MB);
    unsigned short* WO  = (unsigned short*)(ws + 8 * MB);
    unsigned short* FWK = (unsigned short*)(ws + 10 * MB);
    unsigned short* FWR = (unsigned short*)(ws + 17 * MB);
    unsigned short* FWV = (unsigned short*)(ws + 19 * MB);
    unsigned short* XN  = (unsigned short*)(ws + 26 * MB);
    unsigned short* MXR = (unsigned short*)(ws + 58 * MB);
    unsigned short* MXK = (unsigned short*)(ws + 90 * MB);
    unsigned short* MXV = (unsigned short*)(ws + 122 * MB);
    unsigned short* MXG = (unsigned short*)(ws + 154 * MB);
    unsigned short* Rb  = (unsigned short*)(ws + 186 * MB);
    unsigned short* Kb  = (unsigned short*)(ws + 218 * MB);
    unsigned short* Vb  = (unsigned short*)(ws + 26 * MB);   // XN dead after mix4
    unsigned short* Gb  = (unsigned short*)(ws + 58 * MB);   // MXR dead after proj3
    unsigned short* AO  = (unsigned short*)(ws + 154 * MB);  // MXG dead after G-gemm
    unsigned short* XK2 = (unsigned short*)(ws + 58 * MB);   // Gb dead after wkv
    unsigned short* XR2 = (unsigned short*)(ws + 90 * MB);   // MXK dead
    unsigned short* KF  = (unsigned short*)(ws + 122 * MB);  // 112 MB, overlaps dead AO/Rb/Kb
    unsigned short* SRb = (unsigned short*)(ws + 26 * MB);   // XN2 dead after mix2
    float*          X0  = (float*)d_out;

    const int NTOK = Bq * Tq;  // 16384
    dim3 blk512(512);
    const int gsq = (NTOK / 256) * (Cq / 128);    // 512 blocks

    f2bf_all_kernel<<<13312, blk, 0, stream>>>(aWr, aWk, aWv, aWg, aWo, fWk, fWr, fWv,
                                               WR, WK, WV, WG, WO, FWK, FWR, FWV);

    ln01_kernel<<<NTOK, blk, 0, stream>>>(x, ln0w, ln0b, ln1w, ln1b, X0, XN);

    mix4_kernel<<<NTOK, blk, 0, stream>>>(XN, atmr, atmk, atmv, atmg,
                                          (ushort4*)MXR, (ushort4*)MXK,
                                          (ushort4*)MXV, (ushort4*)MXG);

    // fused R/K/V projections (outputs do not alias any concurrent input)
    proj3_kernel<<<1536, blk512, 0, stream>>>(MXR, MXK, MXV, WR, WK, WV, Rb, Kb, Vb);
    // G projection (silu) after proj3 so Gb can reuse MXR's region
    gemm128<1><<<gsq, blk512, 0, stream>>>(MXG, WG, Cq, Cq, nullptr, Gb, nullptr, nullptr);

    wkv_kernel<<<Bq * Hq, blk, 0, stream>>>(Rb, Kb, Vb, Gb, decay, faaaa, lnxw, lnxb, AO);
    gemm128<2><<<gsq, blk512, 0, stream>>>(AO, WO, Cq, Cq, X0, nullptr, X0, nullptr);

    ln_kernel<<<NTOK, blk, 0, stream>>>(X0, ln2w, ln2b, XN);
    mix2_kernel<<<NTOK, blk, 0, stream>>>(XN, ftmk, ftmr, (ushort4*)XK2, (ushort4*)XR2);
    // fused FFN up (relu^2) + sigmoid gate gemms (disjoint in/out regions)
    ffn2_kernel<<<2304, blk512, 0, stream>>>(XK2, FWK, KF, XR2, FWR, SRb);
    gemm128<5><<<gsq, blk512, 0, stream>>>(KF, FWV, FFNq, Cq, X0, nullptr, X0, SRb);
}